// Round 1
// baseline (810.585 us; speedup 1.0000x reference)
//
#include <hip/hip_runtime.h>
#include <hip/hip_bf16.h>
#include <math.h>

#define NRES 512
#define CS 384
#define CZ 128
#define NH 12
#define CDIM 16
#define PQ 4
#define PV 8
#define OUT_DIM 2112   // H*(C + 3*PV + PV + CZ)

__device__ __forceinline__ float softplusf(float x) { return log1pf(expf(x)); }

// ---------------------------------------------------------------------------
// Generic row-staged GEMM: C[m,n] = act( A[m,:]@B[:,n] + bias[n] + res[m,n] )
// grid = (M, ceil(Nc/256)), block = 256, dynamic LDS = K floats
// ---------------------------------------------------------------------------
__global__ void gemm_rowtile(const float* __restrict__ A, const float* __restrict__ B,
                             const float* __restrict__ bias, const float* __restrict__ res,
                             float* __restrict__ C, int M, int K, int Nc, int relu)
{
    extern __shared__ float Alds[];
    int m = blockIdx.x;
    for (int k = threadIdx.x; k < K; k += blockDim.x) Alds[k] = A[(size_t)m * K + k];
    __syncthreads();
    int n = blockIdx.y * blockDim.x + threadIdx.x;
    if (n >= Nc) return;
    float acc = 0.f;
    for (int k = 0; k < K; ++k) acc = fmaf(Alds[k], B[(size_t)k * Nc + n], acc);
    if (bias) acc += bias[n];
    if (res)  acc += res[(size_t)m * Nc + n];
    if (relu) acc = fmaxf(acc, 0.f);
    C[(size_t)m * Nc + n] = acc;
}

// ---------------------------------------------------------------------------
// Frames: gq/gk/gv = rot@{qp,kp,vp} + trans ; sq_q/sq_k
// one thread per residue
// ---------------------------------------------------------------------------
__global__ void frames_kernel(const float* __restrict__ qp, const float* __restrict__ kp,
                              const float* __restrict__ vp, const float* __restrict__ rot,
                              const float* __restrict__ trans,
                              float* __restrict__ gq, float* __restrict__ gk,
                              float* __restrict__ gv, float* __restrict__ sqq,
                              float* __restrict__ sqk)
{
    int n = blockIdx.x * blockDim.x + threadIdx.x;
    if (n >= NRES) return;
    float R[9], t[3];
#pragma unroll
    for (int r = 0; r < 9; ++r) R[r] = rot[n * 9 + r];
#pragma unroll
    for (int r = 0; r < 3; ++r) t[r] = trans[n * 3 + r];

    for (int h = 0; h < NH; ++h) {
        float sq = 0.f, sk = 0.f;
        for (int p = 0; p < PQ; ++p) {
            const float* in = qp + (size_t)n * (NH * PQ * 3) + h * (PQ * 3) + p * 3;
            float* og = gq + (size_t)n * (NH * PQ * 3) + h * (PQ * 3) + p * 3;
#pragma unroll
            for (int a = 0; a < 3; ++a) {
                float g = R[a*3+0]*in[0] + R[a*3+1]*in[1] + R[a*3+2]*in[2] + t[a];
                og[a] = g; sq += g * g;
            }
            const float* in2 = kp + (size_t)n * (NH * PQ * 3) + h * (PQ * 3) + p * 3;
            float* ok = gk + (size_t)n * (NH * PQ * 3) + h * (PQ * 3) + p * 3;
#pragma unroll
            for (int a = 0; a < 3; ++a) {
                float g = R[a*3+0]*in2[0] + R[a*3+1]*in2[1] + R[a*3+2]*in2[2] + t[a];
                ok[a] = g; sk += g * g;
            }
        }
        sqq[n * NH + h] = sq;
        sqk[n * NH + h] = sk;
        for (int p = 0; p < PV; ++p) {
            const float* in = vp + (size_t)n * (NH * PV * 3) + h * (PV * 3) + p * 3;
            float* og = gv + (size_t)n * (NH * PV * 3) + h * (PV * 3) + p * 3;
#pragma unroll
            for (int a = 0; a < 3; ++a)
                og[a] = R[a*3+0]*in[0] + R[a*3+1]*in[1] + R[a*3+2]*in[2] + t[a];
        }
    }
}

// ---------------------------------------------------------------------------
// Logits: L[i,h,j] = WL*( qk*C^-0.5 + bias - 0.5*WC*gamma[h]*d2 )
// block per i (256 threads), j tiled by 64 with padded LDS staging of pair
// ---------------------------------------------------------------------------
#define JT 64
__global__ void logits_kernel(const float* __restrict__ pair, const float* __restrict__ q,
                              const float* __restrict__ k, const float* __restrict__ gq,
                              const float* __restrict__ gk, const float* __restrict__ sqq,
                              const float* __restrict__ sqk, const float* __restrict__ Wb,
                              const float* __restrict__ gamma_raw, float* __restrict__ L)
{
    __shared__ float pl[JT][129];
    __shared__ float qi[192], gqi[144], sqi[12], wb[128 * 12], gam[12];
    int i = blockIdx.x;
    int t = threadIdx.x;

    for (int x = t; x < 192; x += 256) qi[x] = q[(size_t)i * 192 + x];
    for (int x = t; x < 144; x += 256) gqi[x] = gq[(size_t)i * 144 + x];
    if (t < 12) { sqi[t] = sqq[i * 12 + t]; gam[t] = softplusf(gamma_raw[t]); }
    for (int x = t; x < 1536; x += 256) wb[x] = Wb[x];

    const float WL = 0.57735026918962576f;   // sqrt(1/3)
    const float WC = 0.23570226039551584f;   // sqrt(2/(9*4))
    const float CINV = 0.25f;                // 16^-0.5

    int jl = t >> 2, hg = t & 3;

    for (int jt = 0; jt < NRES; jt += JT) {
        __syncthreads();
        for (int x = t; x < JT * 128; x += 256) {
            int jj = x >> 7, z = x & 127;
            pl[jj][z] = pair[(size_t)i * NRES * CZ + (size_t)(jt + jj) * CZ + z];
        }
        __syncthreads();
        int j = jt + jl;
#pragma unroll
        for (int hh = 0; hh < 3; ++hh) {
            int h = hg * 3 + hh;
            float bias = 0.f;
            for (int z = 0; z < 128; ++z) bias = fmaf(pl[jl][z], wb[z * 12 + h], bias);
            float qk = 0.f;
            const float* kj = &k[(size_t)j * 192 + h * 16];
            const float* qh = &qi[h * 16];
#pragma unroll
            for (int c = 0; c < 16; ++c) qk = fmaf(qh[c], kj[c], qk);
            float cross = 0.f;
            const float* gkj = &gk[(size_t)j * 144 + h * 12];
            const float* gqh = &gqi[h * 12];
#pragma unroll
            for (int x = 0; x < 12; ++x) cross = fmaf(gqh[x], gkj[x], cross);
            float d2 = sqi[h] + sqk[j * 12 + h] - 2.f * cross;
            float logit = WL * (qk * CINV + bias - 0.5f * WC * gam[h] * d2);
            L[((size_t)i * NH + h) * NRES + j] = logit;
        }
    }
}

// ---------------------------------------------------------------------------
// Softmax over j for each (i,h) row of L (in place). block = 256, grid = 6144
// ---------------------------------------------------------------------------
__global__ void softmax_kernel(float* __restrict__ L)
{
    int row = blockIdx.x;
    float* p = L + (size_t)row * NRES;
    int t = threadIdx.x;
    __shared__ float red[256];
    float v0 = p[t], v1 = p[t + 256];
    red[t] = fmaxf(v0, v1);
    __syncthreads();
    for (int s = 128; s > 0; s >>= 1) { if (t < s) red[t] = fmaxf(red[t], red[t + s]); __syncthreads(); }
    float m = red[0];
    __syncthreads();
    float e0 = expf(v0 - m), e1 = expf(v1 - m);
    red[t] = e0 + e1;
    __syncthreads();
    for (int s = 128; s > 0; s >>= 1) { if (t < s) red[t] += red[t + s]; __syncthreads(); }
    float inv = 1.f / red[0];
    p[t] = e0 * inv;
    p[t + 256] = e1 * inv;
}

// ---------------------------------------------------------------------------
// o_pair[i,h,z] = sum_j a[i,h,j] * pair[i,j,z]  -> concat[i, 576 + h*128 + z]
// block per i, 256 threads: (z = t&127, hg = t>>7 covering 6 heads each)
// ---------------------------------------------------------------------------
__global__ void opair_kernel(const float* __restrict__ pair, const float* __restrict__ A,
                             float* __restrict__ concat)
{
    int i = blockIdx.x;
    int t = threadIdx.x;
    __shared__ float al[NH * NRES];
    for (int x = t; x < NH * NRES; x += 256) al[x] = A[(size_t)i * NH * NRES + x];
    __syncthreads();
    int z = t & 127, hg = t >> 7;
    float acc[6] = {0.f, 0.f, 0.f, 0.f, 0.f, 0.f};
    const float* pr = pair + (size_t)i * NRES * CZ;
    for (int j = 0; j < NRES; ++j) {
        float pz = pr[(size_t)j * CZ + z];
#pragma unroll
        for (int hh = 0; hh < 6; ++hh)
            acc[hh] = fmaf(al[(hg * 6 + hh) * NRES + j], pz, acc[hh]);
    }
    float* c = concat + (size_t)i * OUT_DIM + 576;
#pragma unroll
    for (int hh = 0; hh < 6; ++hh) c[(hg * 6 + hh) * 128 + z] = acc[hh];
}

// ---------------------------------------------------------------------------
// o_v, o_pt, local, norms  -> concat[i, 0..575]
// block per i, 256 threads
// ---------------------------------------------------------------------------
__global__ void ov_opt_kernel(const float* __restrict__ A, const float* __restrict__ v,
                              const float* __restrict__ gv, const float* __restrict__ rot,
                              const float* __restrict__ trans, float* __restrict__ concat)
{
    int i = blockIdx.x;
    int t = threadIdx.x;
    __shared__ float al[NH * NRES];
    __shared__ float opt[NH * PV * 3];
    for (int x = t; x < NH * NRES; x += 256) al[x] = A[(size_t)i * NH * NRES + x];
    __syncthreads();

    if (t < 192) {  // o_v element (h*16+c)
        int h = t >> 4;
        float acc = 0.f;
        for (int j = 0; j < NRES; ++j) acc = fmaf(al[h * NRES + j], v[(size_t)j * 192 + t], acc);
        concat[(size_t)i * OUT_DIM + t] = acc;
    }
    for (int e = t; e < NH * PV * 3; e += 256) {  // o_pt element (h*24+p*3+c)
        int h = e / 24;
        float acc = 0.f;
        for (int j = 0; j < NRES; ++j) acc = fmaf(al[h * NRES + j], gv[(size_t)j * 288 + e], acc);
        opt[e] = acc;
    }
    __syncthreads();
    if (t < NH * PV) {  // h*8+p
        int h = t >> 3, p = t & 7;
        float b0 = opt[h * 24 + p * 3 + 0] - trans[i * 3 + 0];
        float b1 = opt[h * 24 + p * 3 + 1] - trans[i * 3 + 1];
        float b2 = opt[h * 24 + p * 3 + 2] - trans[i * 3 + 2];
        const float* Ri = rot + i * 9;
        float l0 = Ri[0] * b0 + Ri[3] * b1 + Ri[6] * b2;
        float l1 = Ri[1] * b0 + Ri[4] * b1 + Ri[7] * b2;
        float l2 = Ri[2] * b0 + Ri[5] * b1 + Ri[8] * b2;
        float* c = concat + (size_t)i * OUT_DIM;
        c[192 + h * 24 + p * 3 + 0] = l0;
        c[192 + h * 24 + p * 3 + 1] = l1;
        c[192 + h * 24 + p * 3 + 2] = l2;
        c[480 + h * 8 + p] = sqrtf(l0 * l0 + l1 * l1 + l2 * l2 + 1e-8f);
    }
}

// ---------------------------------------------------------------------------
// LayerNorm over 384: block = 128 (3 elems/thread), grid = 512
// ---------------------------------------------------------------------------
__global__ void ln_kernel(const float* __restrict__ x, const float* __restrict__ g,
                          const float* __restrict__ b, float* __restrict__ y)
{
    int i = blockIdx.x, t = threadIdx.x;
    const float* xr = x + (size_t)i * CS;
    float a0 = xr[t], a1 = xr[t + 128], a2 = xr[t + 256];
    __shared__ float red[128];
    red[t] = a0 + a1 + a2;
    __syncthreads();
    for (int s = 64; s > 0; s >>= 1) { if (t < s) red[t] += red[t + s]; __syncthreads(); }
    float mean = red[0] * (1.f / CS);
    __syncthreads();
    float d0 = a0 - mean, d1 = a1 - mean, d2 = a2 - mean;
    red[t] = d0 * d0 + d1 * d1 + d2 * d2;
    __syncthreads();
    for (int s = 64; s > 0; s >>= 1) { if (t < s) red[t] += red[t + s]; __syncthreads(); }
    float rstd = rsqrtf(red[0] * (1.f / CS) + 1e-5f);
    float* yr = y + (size_t)i * CS;
    yr[t]       = d0 * rstd * g[t]       + b[t];
    yr[t + 128] = d1 * rstd * g[t + 128] + b[t + 128];
    yr[t + 256] = d2 * rstd * g[t + 256] + b[t + 256];
}

// ---------------------------------------------------------------------------
// Backbone update: upd = s@Wbu+bbu ; quat->R ; rot_new = rot@R ; trans_new
// one thread per residue
// ---------------------------------------------------------------------------
__global__ void backbone_kernel(const float* __restrict__ sfin, const float* __restrict__ Wbu,
                                const float* __restrict__ bbu, const float* __restrict__ rot,
                                const float* __restrict__ trans, float* __restrict__ rot_out,
                                float* __restrict__ trans_out)
{
    int i = blockIdx.x * blockDim.x + threadIdx.x;
    if (i >= NRES) return;
    float u[6];
#pragma unroll
    for (int c = 0; c < 6; ++c) {
        float acc = bbu[c];
        for (int k = 0; k < CS; ++k) acc = fmaf(sfin[(size_t)i * CS + k], Wbu[k * 6 + c], acc);
        u[c] = acc;
    }
    float a = 1.f, b = u[0], c2 = u[1], d = u[2];
    float inv = rsqrtf(a * a + b * b + c2 * c2 + d * d);
    a *= inv; b *= inv; c2 *= inv; d *= inv;
    float R[9] = { a*a + b*b - c2*c2 - d*d, 2.f*(b*c2 - a*d),        2.f*(b*d + a*c2),
                   2.f*(b*c2 + a*d),        a*a - b*b + c2*c2 - d*d, 2.f*(c2*d - a*b),
                   2.f*(b*d - a*c2),        2.f*(c2*d + a*b),        a*a - b*b - c2*c2 + d*d };
    const float* Ri = rot + i * 9;
    float Rn[9];
#pragma unroll
    for (int r = 0; r < 3; ++r)
#pragma unroll
        for (int cc = 0; cc < 3; ++cc) {
            float s = 0.f;
#pragma unroll
            for (int kk = 0; kk < 3; ++kk) s += Ri[r * 3 + kk] * R[kk * 3 + cc];
            Rn[r * 3 + cc] = s;
        }
#pragma unroll
    for (int r = 0; r < 9; ++r) rot_out[i * 9 + r] = Rn[r];
    float t0 = u[3], t1 = u[4], t2 = u[5];
#pragma unroll
    for (int r = 0; r < 3; ++r)
        trans_out[i * 3 + r] = Ri[r * 3 + 0] * t0 + Ri[r * 3 + 1] * t1 + Ri[r * 3 + 2] * t2 + trans[i * 3 + r];
}

// ---------------------------------------------------------------------------
// FAPE-ish loss. block per i, 256 threads over j; scaled atomicAdd.
// ---------------------------------------------------------------------------
__global__ void loss_kernel(const float* __restrict__ rot_new, const float* __restrict__ trans_new,
                            const float* __restrict__ rot_truth, const float* __restrict__ trans_truth,
                            float* __restrict__ loss)
{
    int i = blockIdx.x;
    int t = threadIdx.x;
    __shared__ float red[256];
    float Rn[9], Rt[9];
#pragma unroll
    for (int r = 0; r < 9; ++r) { Rn[r] = rot_new[i * 9 + r]; Rt[r] = rot_truth[i * 9 + r]; }
    float ti0 = trans_new[i * 3 + 0], ti1 = trans_new[i * 3 + 1], ti2 = trans_new[i * 3 + 2];
    float tt0 = trans_truth[i * 3 + 0], tt1 = trans_truth[i * 3 + 1], tt2 = trans_truth[i * 3 + 2];
    float s = 0.f;
    for (int j = t; j < NRES; j += 256) {
        float db0 = trans_new[j * 3 + 0] - ti0;
        float db1 = trans_new[j * 3 + 1] - ti1;
        float db2 = trans_new[j * 3 + 2] - ti2;
        float dp0 = Rn[0] * db0 + Rn[3] * db1 + Rn[6] * db2;
        float dp1 = Rn[1] * db0 + Rn[4] * db1 + Rn[7] * db2;
        float dp2 = Rn[2] * db0 + Rn[5] * db1 + Rn[8] * db2;
        float eb0 = trans_truth[j * 3 + 0] - tt0;
        float eb1 = trans_truth[j * 3 + 1] - tt1;
        float eb2 = trans_truth[j * 3 + 2] - tt2;
        float dt0 = Rt[0] * eb0 + Rt[3] * eb1 + Rt[6] * eb2;
        float dt1 = Rt[1] * eb0 + Rt[4] * eb1 + Rt[7] * eb2;
        float dt2 = Rt[2] * eb0 + Rt[5] * eb1 + Rt[8] * eb2;
        float dx = dp0 - dt0, dy = dp1 - dt1, dz = dp2 - dt2;
        float dd = sqrtf(dx * dx + dy * dy + dz * dz + 1e-12f);
        s += fminf(dd, 10.f);
    }
    red[t] = s;
    __syncthreads();
    for (int k = 128; k > 0; k >>= 1) { if (t < k) red[t] += red[t + k]; __syncthreads(); }
    if (t == 0) atomicAdd(loss, red[0] * (1.f / (512.f * 512.f * 10.f)));
}

// ---------------------------------------------------------------------------
extern "C" void kernel_launch(void* const* d_in, const int* in_sizes, int n_in,
                              void* d_out, int out_size, void* d_ws, size_t ws_size,
                              hipStream_t stream)
{
    const float* single      = (const float*)d_in[0];
    const float* pair        = (const float*)d_in[1];
    const float* rot         = (const float*)d_in[2];
    const float* trans       = (const float*)d_in[3];
    const float* rot_truth   = (const float*)d_in[4];
    const float* trans_truth = (const float*)d_in[5];
    const float* Wq  = (const float*)d_in[6];
    const float* Wk  = (const float*)d_in[7];
    const float* Wv  = (const float*)d_in[8];
    const float* Wqp = (const float*)d_in[9];
    const float* Wkp = (const float*)d_in[10];
    const float* Wvp = (const float*)d_in[11];
    const float* Wb  = (const float*)d_in[12];
    const float* Wo  = (const float*)d_in[13];
    const float* bo  = (const float*)d_in[14];
    const float* gamma_raw = (const float*)d_in[15];
    const float* ln1_g = (const float*)d_in[16];
    const float* ln1_b = (const float*)d_in[17];
    const float* ln2_g = (const float*)d_in[18];
    const float* ln2_b = (const float*)d_in[19];
    const float* W1 = (const float*)d_in[20];
    const float* b1 = (const float*)d_in[21];
    const float* W2 = (const float*)d_in[22];
    const float* b2 = (const float*)d_in[23];
    const float* W3 = (const float*)d_in[24];
    const float* b3 = (const float*)d_in[25];
    const float* Wbu = (const float*)d_in[26];
    const float* bbu = (const float*)d_in[27];

    float* out = (float*)d_out;
    float* single_out = out;                   // 512*384
    float* rot_out    = out + 196608;          // 512*9
    float* trans_out  = out + 201216;          // 512*3
    float* loss_out   = out + 202752;          // 1

    float* ws = (float*)d_ws;
    float* q   = ws;                float* k_  = q   + 98304;
    float* v   = k_  + 98304;       float* qp  = v   + 98304;
    float* kp  = qp  + 73728;       float* vp  = kp  + 73728;
    float* gq  = vp  + 147456;      float* gk  = gq  + 73728;
    float* gv  = gk  + 73728;       float* sqq = gv  + 147456;
    float* sqk = sqq + 6144;        float* Amat   = sqk + 6144;      // 512*12*512
    float* concat = Amat + 3145728; float* out1   = concat + 1081344;
    float* sln = out1 + 196608;     float* h1  = sln + 196608;
    float* h2  = h1  + 196608;      float* out2 = h2 + 196608;

    dim3 b256(256);
    size_t lds384 = 384 * sizeof(float);
    size_t lds2112 = 2112 * sizeof(float);

    // projections
    gemm_rowtile<<<dim3(NRES, 1), b256, lds384, stream>>>(single, Wq,  nullptr, nullptr, q,  NRES, CS, 192, 0);
    gemm_rowtile<<<dim3(NRES, 1), b256, lds384, stream>>>(single, Wk,  nullptr, nullptr, k_, NRES, CS, 192, 0);
    gemm_rowtile<<<dim3(NRES, 1), b256, lds384, stream>>>(single, Wv,  nullptr, nullptr, v,  NRES, CS, 192, 0);
    gemm_rowtile<<<dim3(NRES, 1), b256, lds384, stream>>>(single, Wqp, nullptr, nullptr, qp, NRES, CS, 144, 0);
    gemm_rowtile<<<dim3(NRES, 1), b256, lds384, stream>>>(single, Wkp, nullptr, nullptr, kp, NRES, CS, 144, 0);
    gemm_rowtile<<<dim3(NRES, 2), b256, lds384, stream>>>(single, Wvp, nullptr, nullptr, vp, NRES, CS, 288, 0);

    frames_kernel<<<dim3(2), b256, 0, stream>>>(qp, kp, vp, rot, trans, gq, gk, gv, sqq, sqk);

    logits_kernel<<<dim3(NRES), b256, 0, stream>>>(pair, q, k_, gq, gk, sqq, sqk, Wb, gamma_raw, Amat);

    softmax_kernel<<<dim3(NRES * NH), b256, 0, stream>>>(Amat);

    opair_kernel<<<dim3(NRES), b256, 0, stream>>>(pair, Amat, concat);
    ov_opt_kernel<<<dim3(NRES), b256, 0, stream>>>(Amat, v, gv, rot, trans, concat);

    // ipa_out = concat @ Wo + bo + single(residual)
    gemm_rowtile<<<dim3(NRES, 2), b256, lds2112, stream>>>(concat, Wo, bo, single, out1, NRES, OUT_DIM, CS, 0);

    ln_kernel<<<dim3(NRES), dim3(128), 0, stream>>>(out1, ln1_g, ln1_b, sln);

    gemm_rowtile<<<dim3(NRES, 2), b256, lds384, stream>>>(sln, W1, b1, nullptr, h1, NRES, CS, CS, 1);
    gemm_rowtile<<<dim3(NRES, 2), b256, lds384, stream>>>(h1, W2, b2, nullptr, h2, NRES, CS, CS, 1);
    gemm_rowtile<<<dim3(NRES, 2), b256, lds384, stream>>>(h2, W3, b3, sln, out2, NRES, CS, CS, 0);

    ln_kernel<<<dim3(NRES), dim3(128), 0, stream>>>(out2, ln2_g, ln2_b, single_out);

    backbone_kernel<<<dim3(2), b256, 0, stream>>>(single_out, Wbu, bbu, rot, trans, rot_out, trans_out);

    hipMemsetAsync(loss_out, 0, sizeof(float), stream);
    loss_kernel<<<dim3(NRES), b256, 0, stream>>>(rot_out, trans_out, rot_truth, trans_truth, loss_out);
}

// Round 2
// 584.028 us; speedup vs baseline: 1.3879x; 1.3879x over previous
//
#include <hip/hip_runtime.h>
#include <hip/hip_bf16.h>
#include <math.h>

#define NRES 512
#define CS 384
#define CZ 128
#define NH 12
#define PQ 4
#define PV 8
#define OUT_DIM 2112   // H*(C + 3*PV + PV + CZ)
#define PRJ 1152       // packed projection width: q192|k192|v192|qp144|kp144|vp288

__device__ __forceinline__ float softplusf(float x) { return log1pf(expf(x)); }

// ---------------------------------------------------------------------------
// Pack 6 projection weight matrices into Bp[384][1152]
// ---------------------------------------------------------------------------
__global__ void pack_proj_kernel(const float* __restrict__ Wq, const float* __restrict__ Wk,
                                 const float* __restrict__ Wv, const float* __restrict__ Wqp,
                                 const float* __restrict__ Wkp, const float* __restrict__ Wvp,
                                 float* __restrict__ Bp)
{
    int x = blockIdx.x * blockDim.x + threadIdx.x;
    if (x >= CS * PRJ) return;
    int k = x / PRJ, c = x % PRJ;
    float v;
    if      (c < 192)  v = Wq [k * 192 + c];
    else if (c < 384)  v = Wk [k * 192 + (c - 192)];
    else if (c < 576)  v = Wv [k * 192 + (c - 384)];
    else if (c < 720)  v = Wqp[k * 144 + (c - 576)];
    else if (c < 864)  v = Wkp[k * 144 + (c - 720)];
    else               v = Wvp[k * 288 + (c - 864)];
    Bp[x] = v;
}

// ---------------------------------------------------------------------------
// Tiled f32 GEMM: BM=64, BN=64, BK=16, 256 threads, 4x4 micro-tile.
// If gridDim.z > 1: k-split partial, atomicAdd into pre-initialized C
// (bias/res/relu ignored). Else: C = act(A@B + bias + res).
// ---------------------------------------------------------------------------
__global__ void gemm_tiled(const float* __restrict__ A, const float* __restrict__ B,
                           const float* __restrict__ bias, const float* __restrict__ res,
                           float* __restrict__ C, int M, int K, int Nc, int relu, int KS)
{
    __shared__ float As[16][68];   // transposed A tile, padded (16B-aligned rows)
    __shared__ float Bs[16][64];
    int m0 = blockIdx.x * 64, n0 = blockIdx.y * 64;
    int kbeg = blockIdx.z * KS;
    int t = threadIdx.x;
    int tm = t >> 4, tn = t & 15;
    int lr = t >> 2, lc4 = t & 3;     // A tile load: row, k-quad
    int br = t >> 4, bc4 = t & 15;    // B tile load: k-row, n-quad
    float acc[4][4] = {{0.f}};

    for (int kt = kbeg; kt < kbeg + KS; kt += 16) {
        float4 a4 = *(const float4*)&A[(size_t)(m0 + lr) * K + kt + lc4 * 4];
        float4 b4 = *(const float4*)&B[(size_t)(kt + br) * Nc + n0 + bc4 * 4];
        As[lc4 * 4 + 0][lr] = a4.x;
        As[lc4 * 4 + 1][lr] = a4.y;
        As[lc4 * 4 + 2][lr] = a4.z;
        As[lc4 * 4 + 3][lr] = a4.w;
        *(float4*)&Bs[br][bc4 * 4] = b4;
        __syncthreads();
#pragma unroll
        for (int k = 0; k < 16; ++k) {
            float4 av = *(const float4*)&As[k][tm * 4];
            float4 bv = *(const float4*)&Bs[k][tn * 4];
            acc[0][0] = fmaf(av.x, bv.x, acc[0][0]); acc[0][1] = fmaf(av.x, bv.y, acc[0][1]);
            acc[0][2] = fmaf(av.x, bv.z, acc[0][2]); acc[0][3] = fmaf(av.x, bv.w, acc[0][3]);
            acc[1][0] = fmaf(av.y, bv.x, acc[1][0]); acc[1][1] = fmaf(av.y, bv.y, acc[1][1]);
            acc[1][2] = fmaf(av.y, bv.z, acc[1][2]); acc[1][3] = fmaf(av.y, bv.w, acc[1][3]);
            acc[2][0] = fmaf(av.z, bv.x, acc[2][0]); acc[2][1] = fmaf(av.z, bv.y, acc[2][1]);
            acc[2][2] = fmaf(av.z, bv.z, acc[2][2]); acc[2][3] = fmaf(av.z, bv.w, acc[2][3]);
            acc[3][0] = fmaf(av.w, bv.x, acc[3][0]); acc[3][1] = fmaf(av.w, bv.y, acc[3][1]);
            acc[3][2] = fmaf(av.w, bv.z, acc[3][2]); acc[3][3] = fmaf(av.w, bv.w, acc[3][3]);
        }
        __syncthreads();
    }

    if (gridDim.z > 1) {
#pragma unroll
        for (int r = 0; r < 4; ++r)
#pragma unroll
            for (int c = 0; c < 4; ++c)
                atomicAdd(&C[(size_t)(m0 + tm * 4 + r) * Nc + n0 + tn * 4 + c], acc[r][c]);
    } else {
#pragma unroll
        for (int r = 0; r < 4; ++r) {
            int row = m0 + tm * 4 + r;
            float4 v;
            float* vp = (float*)&v;
#pragma unroll
            for (int c = 0; c < 4; ++c) {
                int col = n0 + tn * 4 + c;
                float x = acc[r][c];
                if (bias) x += bias[col];
                if (res)  x += res[(size_t)row * Nc + col];
                if (relu) x = fmaxf(x, 0.f);
                vp[c] = x;
            }
            *(float4*)&C[(size_t)row * Nc + n0 + tn * 4] = v;
        }
    }
}

// ---------------------------------------------------------------------------
// out1[m][n] = bo[n] + single[m][n]  (pre-init for atomic Wo GEMM)
// ---------------------------------------------------------------------------
__global__ void init_out1_kernel(const float* __restrict__ bo, const float* __restrict__ single,
                                 float* __restrict__ out1)
{
    int x = blockIdx.x * blockDim.x + threadIdx.x;
    if (x >= NRES * CS) return;
    out1[x] = bo[x % CS] + single[x];
}

// ---------------------------------------------------------------------------
// Frames: gq/gk/gv = rot@{qp,kp,vp} + trans ; sq_q/sq_k. proj-packed input.
// ---------------------------------------------------------------------------
__global__ void frames_kernel(const float* __restrict__ proj, const float* __restrict__ rot,
                              const float* __restrict__ trans,
                              float* __restrict__ gq, float* __restrict__ gk,
                              float* __restrict__ gv, float* __restrict__ sqq,
                              float* __restrict__ sqk)
{
    int n = blockIdx.x * blockDim.x + threadIdx.x;
    if (n >= NRES) return;
    float R[9], t3[3];
#pragma unroll
    for (int r = 0; r < 9; ++r) R[r] = rot[n * 9 + r];
#pragma unroll
    for (int r = 0; r < 3; ++r) t3[r] = trans[n * 3 + r];
    const float* qp = proj + (size_t)n * PRJ + 576;
    const float* kp = proj + (size_t)n * PRJ + 720;
    const float* vp = proj + (size_t)n * PRJ + 864;

    for (int h = 0; h < NH; ++h) {
        float sq = 0.f, sk = 0.f;
        for (int p = 0; p < PQ; ++p) {
            const float* in = qp + h * (PQ * 3) + p * 3;
            float* og = gq + (size_t)n * 144 + h * (PQ * 3) + p * 3;
#pragma unroll
            for (int a = 0; a < 3; ++a) {
                float g = R[a*3+0]*in[0] + R[a*3+1]*in[1] + R[a*3+2]*in[2] + t3[a];
                og[a] = g; sq += g * g;
            }
            const float* in2 = kp + h * (PQ * 3) + p * 3;
            float* ok = gk + (size_t)n * 144 + h * (PQ * 3) + p * 3;
#pragma unroll
            for (int a = 0; a < 3; ++a) {
                float g = R[a*3+0]*in2[0] + R[a*3+1]*in2[1] + R[a*3+2]*in2[2] + t3[a];
                ok[a] = g; sk += g * g;
            }
        }
        sqq[n * NH + h] = sq;
        sqk[n * NH + h] = sk;
        for (int p = 0; p < PV; ++p) {
            const float* in = vp + h * (PV * 3) + p * 3;
            float* og = gv + (size_t)n * 288 + h * (PV * 3) + p * 3;
#pragma unroll
            for (int a = 0; a < 3; ++a)
                og[a] = R[a*3+0]*in[0] + R[a*3+1]*in[1] + R[a*3+2]*in[2] + t3[a];
        }
    }
}

// ---------------------------------------------------------------------------
// Logits v2: block per i. thread = (j in tile of 64, head-group of 3).
// pair tile XOR-swizzled in LDS (conflict-free b128); Wb repacked [z][4][4].
// Writes L[i][h][j] (pre-softmax).
// ---------------------------------------------------------------------------
__global__ void logits_kernel(const float* __restrict__ pair, const float* __restrict__ proj,
                              const float* __restrict__ gq, const float* __restrict__ gk,
                              const float* __restrict__ sqq, const float* __restrict__ sqk,
                              const float* __restrict__ Wb, const float* __restrict__ gamma_raw,
                              float* __restrict__ L)
{
    __shared__ float pl[64][128];      // XOR-swizzled quads
    __shared__ float wbp[128][16];     // wbp[z][hc*4 + hh] = Wb[z][hc*3+hh]
    __shared__ float qi[192], gqi[144], sqi[12], gam[12];
    int i = blockIdx.x, t = threadIdx.x;

    for (int x = t; x < 192; x += 256) qi[x] = proj[(size_t)i * PRJ + x];
    for (int x = t; x < 144; x += 256) gqi[x] = gq[(size_t)i * 144 + x];
    if (t < 12) { sqi[t] = sqq[i * 12 + t]; gam[t] = softplusf(gamma_raw[t]); }
    for (int x = t; x < 128 * 16; x += 256) wbp[x >> 4][x & 15] = 0.f;
    __syncthreads();
    for (int x = t; x < 128 * 12; x += 256) {
        int z = x / 12, h = x % 12;
        wbp[z][(h / 3) * 4 + (h % 3)] = Wb[x];
    }

    const float WLc = 0.57735026918962576f;   // sqrt(1/3)
    const float WCc = 0.23570226039551584f;   // sqrt(2/(9*4))
    int j_lo = t & 63, hc = t >> 6;

    for (int jt = 0; jt < NRES; jt += 64) {
        __syncthreads();
        for (int x = t; x < 64 * 32; x += 256) {
            int jj = x >> 5, zq = x & 31;
            float4 v = *(const float4*)&pair[((size_t)i * NRES + jt + jj) * CZ + zq * 4];
            ((float4*)pl[jj])[zq ^ (jj & 31)] = v;
        }
        __syncthreads();

        int j = jt + j_lo;
        float b0 = 0.f, b1 = 0.f, b2 = 0.f;
#pragma unroll
        for (int zq = 0; zq < 32; ++zq) {
            float4 p4 = ((const float4*)pl[j_lo])[zq ^ (j_lo & 31)];
#pragma unroll
            for (int c = 0; c < 4; ++c) {
                float pz = ((const float*)&p4)[c];
                float4 w = *(const float4*)&wbp[zq * 4 + c][hc * 4];
                b0 = fmaf(pz, w.x, b0);
                b1 = fmaf(pz, w.y, b1);
                b2 = fmaf(pz, w.z, b2);
            }
        }
        float bias_h[3] = {b0, b1, b2};
        const float* kj  = &proj[(size_t)j * PRJ + 192];
        const float* gkj = &gk[(size_t)j * 144];
#pragma unroll
        for (int hh = 0; hh < 3; ++hh) {
            int h = hc * 3 + hh;
            float qk = 0.f;
#pragma unroll
            for (int c = 0; c < 16; ++c) qk = fmaf(qi[h * 16 + c], kj[h * 16 + c], qk);
            float cross = 0.f;
#pragma unroll
            for (int x = 0; x < 12; ++x) cross = fmaf(gqi[h * 12 + x], gkj[h * 12 + x], cross);
            float d2 = sqi[h] + sqk[j * 12 + h] - 2.f * cross;
            L[((size_t)i * NH + h) * NRES + j] =
                WLc * (qk * 0.25f + bias_h[hh] - 0.5f * WCc * gam[h] * d2);
        }
    }
}

// ---------------------------------------------------------------------------
// Softmax over j per (i,h) row, in place. grid = 6144, block = 256
// ---------------------------------------------------------------------------
__global__ void softmax_kernel(float* __restrict__ L)
{
    int row = blockIdx.x;
    float* p = L + (size_t)row * NRES;
    int t = threadIdx.x;
    __shared__ float red[256];
    float v0 = p[t], v1 = p[t + 256];
    red[t] = fmaxf(v0, v1);
    __syncthreads();
    for (int s = 128; s > 0; s >>= 1) { if (t < s) red[t] = fmaxf(red[t], red[t + s]); __syncthreads(); }
    float m = red[0];
    __syncthreads();
    float e0 = expf(v0 - m), e1 = expf(v1 - m);
    red[t] = e0 + e1;
    __syncthreads();
    for (int s = 128; s > 0; s >>= 1) { if (t < s) red[t] += red[t + s]; __syncthreads(); }
    float inv = 1.f / red[0];
    p[t] = e0 * inv;
    p[t + 256] = e1 * inv;
}

// ---------------------------------------------------------------------------
// o_pair: block per i, 384 threads = (32 z-quads x 12 heads). float4 pair loads.
// ---------------------------------------------------------------------------
__global__ void opair_kernel(const float* __restrict__ pair, const float* __restrict__ A,
                             float* __restrict__ concat)
{
    __shared__ float al[NH * NRES];
    int i = blockIdx.x, t = threadIdx.x;
    for (int x = t; x < NH * NRES / 4; x += 384)
        *(float4*)&al[x * 4] = *(const float4*)&A[(size_t)i * NH * NRES + x * 4];
    __syncthreads();
    int zq = t & 31, h = t >> 5;
    float4 acc = {0.f, 0.f, 0.f, 0.f};
    const float* pr = pair + (size_t)i * NRES * CZ;
    const float* ah = al + h * NRES;
    for (int j = 0; j < NRES; ++j) {
        float4 p4 = *(const float4*)&pr[(size_t)j * CZ + zq * 4];
        float a = ah[j];
        acc.x = fmaf(a, p4.x, acc.x);
        acc.y = fmaf(a, p4.y, acc.y);
        acc.z = fmaf(a, p4.z, acc.z);
        acc.w = fmaf(a, p4.w, acc.w);
    }
    *(float4*)&concat[(size_t)i * OUT_DIM + 576 + h * 128 + zq * 4] = acc;
}

// ---------------------------------------------------------------------------
// o_v, o_pt, local, norms -> concat[i, 0..575]. block per i, 256 threads.
// ---------------------------------------------------------------------------
__global__ void ov_opt_kernel(const float* __restrict__ A, const float* __restrict__ proj,
                              const float* __restrict__ gv, const float* __restrict__ rot,
                              const float* __restrict__ trans, float* __restrict__ concat)
{
    int i = blockIdx.x, t = threadIdx.x;
    __shared__ float al[NH * NRES];
    __shared__ float opt[NH * PV * 3];
    for (int x = t; x < NH * NRES; x += 256) al[x] = A[(size_t)i * NH * NRES + x];
    __syncthreads();

    if (t < 192) {  // o_v element (h*16+c)
        int h = t >> 4;
        float acc = 0.f;
        for (int j = 0; j < NRES; ++j)
            acc = fmaf(al[h * NRES + j], proj[(size_t)j * PRJ + 384 + t], acc);
        concat[(size_t)i * OUT_DIM + t] = acc;
    }
    for (int e = t; e < NH * PV * 3; e += 256) {  // o_pt element (h*24+p*3+c)
        int h = e / 24;
        float acc = 0.f;
        for (int j = 0; j < NRES; ++j) acc = fmaf(al[h * NRES + j], gv[(size_t)j * 288 + e], acc);
        opt[e] = acc;
    }
    __syncthreads();
    if (t < NH * PV) {  // h*8+p
        int h = t >> 3, p = t & 7;
        float b0 = opt[h * 24 + p * 3 + 0] - trans[i * 3 + 0];
        float b1 = opt[h * 24 + p * 3 + 1] - trans[i * 3 + 1];
        float b2 = opt[h * 24 + p * 3 + 2] - trans[i * 3 + 2];
        const float* Ri = rot + i * 9;
        float l0 = Ri[0] * b0 + Ri[3] * b1 + Ri[6] * b2;
        float l1 = Ri[1] * b0 + Ri[4] * b1 + Ri[7] * b2;
        float l2 = Ri[2] * b0 + Ri[5] * b1 + Ri[8] * b2;
        float* c = concat + (size_t)i * OUT_DIM;
        c[192 + h * 24 + p * 3 + 0] = l0;
        c[192 + h * 24 + p * 3 + 1] = l1;
        c[192 + h * 24 + p * 3 + 2] = l2;
        c[480 + h * 8 + p] = sqrtf(l0 * l0 + l1 * l1 + l2 * l2 + 1e-8f);
    }
}

// ---------------------------------------------------------------------------
// LayerNorm over 384: block = 128, grid = 512
// ---------------------------------------------------------------------------
__global__ void ln_kernel(const float* __restrict__ x, const float* __restrict__ g,
                          const float* __restrict__ b, float* __restrict__ y)
{
    int i = blockIdx.x, t = threadIdx.x;
    const float* xr = x + (size_t)i * CS;
    float a0 = xr[t], a1 = xr[t + 128], a2 = xr[t + 256];
    __shared__ float red[128];
    red[t] = a0 + a1 + a2;
    __syncthreads();
    for (int s = 64; s > 0; s >>= 1) { if (t < s) red[t] += red[t + s]; __syncthreads(); }
    float mean = red[0] * (1.f / CS);
    __syncthreads();
    float d0 = a0 - mean, d1 = a1 - mean, d2 = a2 - mean;
    red[t] = d0 * d0 + d1 * d1 + d2 * d2;
    __syncthreads();
    for (int s = 64; s > 0; s >>= 1) { if (t < s) red[t] += red[t + s]; __syncthreads(); }
    float rstd = rsqrtf(red[0] * (1.f / CS) + 1e-5f);
    float* yr = y + (size_t)i * CS;
    yr[t]       = d0 * rstd * g[t]       + b[t];
    yr[t + 128] = d1 * rstd * g[t + 128] + b[t + 128];
    yr[t + 256] = d2 * rstd * g[t + 256] + b[t + 256];
}

// ---------------------------------------------------------------------------
// Backbone update
// ---------------------------------------------------------------------------
__global__ void backbone_kernel(const float* __restrict__ sfin, const float* __restrict__ Wbu,
                                const float* __restrict__ bbu, const float* __restrict__ rot,
                                const float* __restrict__ trans, float* __restrict__ rot_out,
                                float* __restrict__ trans_out)
{
    int i = blockIdx.x * blockDim.x + threadIdx.x;
    if (i >= NRES) return;
    float u[6];
#pragma unroll
    for (int c = 0; c < 6; ++c) {
        float acc = bbu[c];
        for (int k = 0; k < CS; ++k) acc = fmaf(sfin[(size_t)i * CS + k], Wbu[k * 6 + c], acc);
        u[c] = acc;
    }
    float a = 1.f, b = u[0], c2 = u[1], d = u[2];
    float inv = rsqrtf(a * a + b * b + c2 * c2 + d * d);
    a *= inv; b *= inv; c2 *= inv; d *= inv;
    float R[9] = { a*a + b*b - c2*c2 - d*d, 2.f*(b*c2 - a*d),        2.f*(b*d + a*c2),
                   2.f*(b*c2 + a*d),        a*a - b*b + c2*c2 - d*d, 2.f*(c2*d - a*b),
                   2.f*(b*d - a*c2),        2.f*(c2*d + a*b),        a*a - b*b - c2*c2 + d*d };
    const float* Ri = rot + i * 9;
    float Rn[9];
#pragma unroll
    for (int r = 0; r < 3; ++r)
#pragma unroll
        for (int cc = 0; cc < 3; ++cc) {
            float s = 0.f;
#pragma unroll
            for (int kk = 0; kk < 3; ++kk) s += Ri[r * 3 + kk] * R[kk * 3 + cc];
            Rn[r * 3 + cc] = s;
        }
#pragma unroll
    for (int r = 0; r < 9; ++r) rot_out[i * 9 + r] = Rn[r];
    float t0 = u[3], t1 = u[4], t2 = u[5];
#pragma unroll
    for (int r = 0; r < 3; ++r)
        trans_out[i * 3 + r] = Ri[r * 3 + 0] * t0 + Ri[r * 3 + 1] * t1 + Ri[r * 3 + 2] * t2 + trans[i * 3 + r];
}

// ---------------------------------------------------------------------------
// Loss
// ---------------------------------------------------------------------------
__global__ void loss_kernel(const float* __restrict__ rot_new, const float* __restrict__ trans_new,
                            const float* __restrict__ rot_truth, const float* __restrict__ trans_truth,
                            float* __restrict__ loss)
{
    int i = blockIdx.x;
    int t = threadIdx.x;
    __shared__ float red[256];
    float Rn[9], Rt[9];
#pragma unroll
    for (int r = 0; r < 9; ++r) { Rn[r] = rot_new[i * 9 + r]; Rt[r] = rot_truth[i * 9 + r]; }
    float ti0 = trans_new[i * 3 + 0], ti1 = trans_new[i * 3 + 1], ti2 = trans_new[i * 3 + 2];
    float tt0 = trans_truth[i * 3 + 0], tt1 = trans_truth[i * 3 + 1], tt2 = trans_truth[i * 3 + 2];
    float s = 0.f;
    for (int j = t; j < NRES; j += 256) {
        float db0 = trans_new[j * 3 + 0] - ti0;
        float db1 = trans_new[j * 3 + 1] - ti1;
        float db2 = trans_new[j * 3 + 2] - ti2;
        float dp0 = Rn[0] * db0 + Rn[3] * db1 + Rn[6] * db2;
        float dp1 = Rn[1] * db0 + Rn[4] * db1 + Rn[7] * db2;
        float dp2 = Rn[2] * db0 + Rn[5] * db1 + Rn[8] * db2;
        float eb0 = trans_truth[j * 3 + 0] - tt0;
        float eb1 = trans_truth[j * 3 + 1] - tt1;
        float eb2 = trans_truth[j * 3 + 2] - tt2;
        float dt0 = Rt[0] * eb0 + Rt[3] * eb1 + Rt[6] * eb2;
        float dt1 = Rt[1] * eb0 + Rt[4] * eb1 + Rt[7] * eb2;
        float dt2 = Rt[2] * eb0 + Rt[5] * eb1 + Rt[8] * eb2;
        float dx = dp0 - dt0, dy = dp1 - dt1, dz = dp2 - dt2;
        float dd = sqrtf(dx * dx + dy * dy + dz * dz + 1e-12f);
        s += fminf(dd, 10.f);
    }
    red[t] = s;
    __syncthreads();
    for (int k = 128; k > 0; k >>= 1) { if (t < k) red[t] += red[t + k]; __syncthreads(); }
    if (t == 0) atomicAdd(loss, red[0] * (1.f / (512.f * 512.f * 10.f)));
}

// ---------------------------------------------------------------------------
extern "C" void kernel_launch(void* const* d_in, const int* in_sizes, int n_in,
                              void* d_out, int out_size, void* d_ws, size_t ws_size,
                              hipStream_t stream)
{
    const float* single      = (const float*)d_in[0];
    const float* pair        = (const float*)d_in[1];
    const float* rot         = (const float*)d_in[2];
    const float* trans       = (const float*)d_in[3];
    const float* rot_truth   = (const float*)d_in[4];
    const float* trans_truth = (const float*)d_in[5];
    const float* Wq  = (const float*)d_in[6];
    const float* Wk  = (const float*)d_in[7];
    const float* Wv  = (const float*)d_in[8];
    const float* Wqp = (const float*)d_in[9];
    const float* Wkp = (const float*)d_in[10];
    const float* Wvp = (const float*)d_in[11];
    const float* Wb  = (const float*)d_in[12];
    const float* Wo  = (const float*)d_in[13];
    const float* bo  = (const float*)d_in[14];
    const float* gamma_raw = (const float*)d_in[15];
    const float* ln1_g = (const float*)d_in[16];
    const float* ln1_b = (const float*)d_in[17];
    const float* ln2_g = (const float*)d_in[18];
    const float* ln2_b = (const float*)d_in[19];
    const float* W1 = (const float*)d_in[20];
    const float* b1 = (const float*)d_in[21];
    const float* W2 = (const float*)d_in[22];
    const float* b2 = (const float*)d_in[23];
    const float* W3 = (const float*)d_in[24];
    const float* b3 = (const float*)d_in[25];
    const float* Wbu = (const float*)d_in[26];
    const float* bbu = (const float*)d_in[27];

    float* out = (float*)d_out;
    float* single_out = out;                   // 512*384
    float* rot_out    = out + 196608;          // 512*9
    float* trans_out  = out + 201216;          // 512*3
    float* loss_out   = out + 202752;          // 1

    float* ws = (float*)d_ws;
    float* proj   = ws;                         // 512*1152 = 589824
    float* gq     = proj   + 589824;            // 73728
    float* gk     = gq     + 73728;             // 73728
    float* gv     = gk     + 73728;             // 147456
    float* sqq    = gv     + 147456;            // 6144
    float* sqk    = sqq    + 6144;              // 6144
    float* Amat   = sqk    + 6144;              // 512*12*512 = 3145728
    float* Bp     = Amat;                       // alias: used only before logits
    float* concat = Amat   + 3145728;           // 512*2112 = 1081344
    float* out1   = concat + 1081344;           // 196608 (also out2)
    float* sln    = out1   + 196608;            // 196608
    float* h1     = sln    + 196608;            // 196608
    float* h2     = h1     + 196608;            // 196608

    dim3 b256(256);

    // 1. pack projection weights, fused projection GEMM
    pack_proj_kernel<<<dim3((CS * PRJ + 255) / 256), b256, 0, stream>>>(Wq, Wk, Wv, Wqp, Wkp, Wvp, Bp);
    gemm_tiled<<<dim3(8, PRJ / 64, 1), b256, 0, stream>>>(single, Bp, nullptr, nullptr, proj,
                                                          NRES, CS, PRJ, 0, CS);

    // 2. frames
    frames_kernel<<<dim3(2), b256, 0, stream>>>(proj, rot, trans, gq, gk, gv, sqq, sqk);

    // 3. logits + softmax
    logits_kernel<<<dim3(NRES), b256, 0, stream>>>(pair, proj, gq, gk, sqq, sqk, Wb, gamma_raw, Amat);
    softmax_kernel<<<dim3(NRES * NH), b256, 0, stream>>>(Amat);

    // 4. attention outputs
    opair_kernel<<<dim3(NRES), dim3(384), 0, stream>>>(pair, Amat, concat);
    ov_opt_kernel<<<dim3(NRES), b256, 0, stream>>>(Amat, proj, gv, rot, trans, concat);

    // 5. ipa_out = concat @ Wo + bo + single  (k-split=4, atomic into pre-init)
    init_out1_kernel<<<dim3((NRES * CS + 255) / 256), b256, 0, stream>>>(bo, single, out1);
    gemm_tiled<<<dim3(8, CS / 64, 4), b256, 0, stream>>>(concat, Wo, nullptr, nullptr, out1,
                                                         NRES, OUT_DIM, CS, 0, 528);

    // 6. LN1 + FF + LN2
    ln_kernel<<<dim3(NRES), dim3(128), 0, stream>>>(out1, ln1_g, ln1_b, sln);
    gemm_tiled<<<dim3(8, CS / 64, 1), b256, 0, stream>>>(sln, W1, b1, nullptr, h1, NRES, CS, CS, 1, CS);
    gemm_tiled<<<dim3(8, CS / 64, 1), b256, 0, stream>>>(h1, W2, b2, nullptr, h2, NRES, CS, CS, 1, CS);
    gemm_tiled<<<dim3(8, CS / 64, 1), b256, 0, stream>>>(h2, W3, b3, sln, out1, NRES, CS, CS, 0, CS);
    ln_kernel<<<dim3(NRES), dim3(128), 0, stream>>>(out1, ln2_g, ln2_b, single_out);

    // 7. backbone + loss
    backbone_kernel<<<dim3(2), b256, 0, stream>>>(single_out, Wbu, bbu, rot, trans, rot_out, trans_out);
    hipMemsetAsync(loss_out, 0, sizeof(float), stream);
    loss_kernel<<<dim3(NRES), b256, 0, stream>>>(rot_out, trans_out, rot_truth, trans_truth, loss_out);
}

// Round 3
// 550.501 us; speedup vs baseline: 1.4724x; 1.0609x over previous
//
#include <hip/hip_runtime.h>
#include <hip/hip_bf16.h>
#include <math.h>

#define NRES 512
#define CS 384
#define CZ 128
#define NH 12
#define PQ 4
#define PV 8
#define OUT_DIM 2112   // H*(C + 3*PV + PV + CZ)
#define PRJ 1152       // packed projection width: q192|k192|v192|qp144|kp144|vp288

typedef __attribute__((ext_vector_type(8))) short short8;
typedef __attribute__((ext_vector_type(4))) float f32x4;

__device__ __forceinline__ float softplusf(float x) { return log1pf(expf(x)); }

__device__ __forceinline__ unsigned short f2bf(float f) {
    union { float f; unsigned u; } v; v.f = f;
    unsigned r = v.u + 0x7FFF + ((v.u >> 16) & 1);
    return (unsigned short)(r >> 16);
}

// ---------------------------------------------------------------------------
// Pack 6 projection weight matrices into Bp[384][1152]
// ---------------------------------------------------------------------------
__global__ void pack_proj_kernel(const float* __restrict__ Wq, const float* __restrict__ Wk,
                                 const float* __restrict__ Wv, const float* __restrict__ Wqp,
                                 const float* __restrict__ Wkp, const float* __restrict__ Wvp,
                                 float* __restrict__ Bp)
{
    int x = blockIdx.x * blockDim.x + threadIdx.x;
    if (x >= CS * PRJ) return;
    int k = x / PRJ, c = x % PRJ;
    float v;
    if      (c < 192)  v = Wq [k * 192 + c];
    else if (c < 384)  v = Wk [k * 192 + (c - 192)];
    else if (c < 576)  v = Wv [k * 192 + (c - 384)];
    else if (c < 720)  v = Wqp[k * 144 + (c - 576)];
    else if (c < 864)  v = Wkp[k * 144 + (c - 720)];
    else               v = Wvp[k * 288 + (c - 864)];
    Bp[x] = v;
}

// ---------------------------------------------------------------------------
// Tiled f32 GEMM: BM=64, BN=64, BK=16, 256 threads, 4x4 micro-tile.
// If gridDim.z > 1: k-split partial, atomicAdd into pre-initialized C.
// ---------------------------------------------------------------------------
__global__ void gemm_tiled(const float* __restrict__ A, const float* __restrict__ B,
                           const float* __restrict__ bias, const float* __restrict__ res,
                           float* __restrict__ C, int M, int K, int Nc, int relu, int KS)
{
    __shared__ float As[16][68];
    __shared__ float Bs[16][64];
    int m0 = blockIdx.x * 64, n0 = blockIdx.y * 64;
    int kbeg = blockIdx.z * KS;
    int t = threadIdx.x;
    int tm = t >> 4, tn = t & 15;
    int lr = t >> 2, lc4 = t & 3;
    int br = t >> 4, bc4 = t & 15;
    float acc[4][4] = {{0.f}};

    for (int kt = kbeg; kt < kbeg + KS; kt += 16) {
        float4 a4 = *(const float4*)&A[(size_t)(m0 + lr) * K + kt + lc4 * 4];
        float4 b4 = *(const float4*)&B[(size_t)(kt + br) * Nc + n0 + bc4 * 4];
        As[lc4 * 4 + 0][lr] = a4.x;
        As[lc4 * 4 + 1][lr] = a4.y;
        As[lc4 * 4 + 2][lr] = a4.z;
        As[lc4 * 4 + 3][lr] = a4.w;
        *(float4*)&Bs[br][bc4 * 4] = b4;
        __syncthreads();
#pragma unroll
        for (int k = 0; k < 16; ++k) {
            float4 av = *(const float4*)&As[k][tm * 4];
            float4 bv = *(const float4*)&Bs[k][tn * 4];
            acc[0][0] = fmaf(av.x, bv.x, acc[0][0]); acc[0][1] = fmaf(av.x, bv.y, acc[0][1]);
            acc[0][2] = fmaf(av.x, bv.z, acc[0][2]); acc[0][3] = fmaf(av.x, bv.w, acc[0][3]);
            acc[1][0] = fmaf(av.y, bv.x, acc[1][0]); acc[1][1] = fmaf(av.y, bv.y, acc[1][1]);
            acc[1][2] = fmaf(av.y, bv.z, acc[1][2]); acc[1][3] = fmaf(av.y, bv.w, acc[1][3]);
            acc[2][0] = fmaf(av.z, bv.x, acc[2][0]); acc[2][1] = fmaf(av.z, bv.y, acc[2][1]);
            acc[2][2] = fmaf(av.z, bv.z, acc[2][2]); acc[2][3] = fmaf(av.z, bv.w, acc[2][3]);
            acc[3][0] = fmaf(av.w, bv.x, acc[3][0]); acc[3][1] = fmaf(av.w, bv.y, acc[3][1]);
            acc[3][2] = fmaf(av.w, bv.z, acc[3][2]); acc[3][3] = fmaf(av.w, bv.w, acc[3][3]);
        }
        __syncthreads();
    }

    if (gridDim.z > 1) {
#pragma unroll
        for (int r = 0; r < 4; ++r)
#pragma unroll
            for (int c = 0; c < 4; ++c)
                atomicAdd(&C[(size_t)(m0 + tm * 4 + r) * Nc + n0 + tn * 4 + c], acc[r][c]);
    } else {
#pragma unroll
        for (int r = 0; r < 4; ++r) {
            int row = m0 + tm * 4 + r;
            float4 v;
            float* vp = (float*)&v;
#pragma unroll
            for (int c = 0; c < 4; ++c) {
                int col = n0 + tn * 4 + c;
                float x = acc[r][c];
                if (bias) x += bias[col];
                if (res)  x += res[(size_t)row * Nc + col];
                if (relu) x = fmaxf(x, 0.f);
                vp[c] = x;
            }
            *(float4*)&C[(size_t)row * Nc + n0 + tn * 4] = v;
        }
    }
}

// ---------------------------------------------------------------------------
__global__ void init_out1_kernel(const float* __restrict__ bo, const float* __restrict__ single,
                                 float* __restrict__ out1)
{
    int x = blockIdx.x * blockDim.x + threadIdx.x;
    if (x >= NRES * CS) return;
    out1[x] = bo[x % CS] + single[x];
}

// ---------------------------------------------------------------------------
// Frames
// ---------------------------------------------------------------------------
__global__ void frames_kernel(const float* __restrict__ proj, const float* __restrict__ rot,
                              const float* __restrict__ trans,
                              float* __restrict__ gq, float* __restrict__ gk,
                              float* __restrict__ gv, float* __restrict__ sqq,
                              float* __restrict__ sqk)
{
    int n = blockIdx.x * blockDim.x + threadIdx.x;
    if (n >= NRES) return;
    float R[9], t3[3];
#pragma unroll
    for (int r = 0; r < 9; ++r) R[r] = rot[n * 9 + r];
#pragma unroll
    for (int r = 0; r < 3; ++r) t3[r] = trans[n * 3 + r];
    const float* qp = proj + (size_t)n * PRJ + 576;
    const float* kp = proj + (size_t)n * PRJ + 720;
    const float* vp = proj + (size_t)n * PRJ + 864;

    for (int h = 0; h < NH; ++h) {
        float sq = 0.f, sk = 0.f;
        for (int p = 0; p < PQ; ++p) {
            const float* in = qp + h * (PQ * 3) + p * 3;
            float* og = gq + (size_t)n * 144 + h * (PQ * 3) + p * 3;
#pragma unroll
            for (int a = 0; a < 3; ++a) {
                float g = R[a*3+0]*in[0] + R[a*3+1]*in[1] + R[a*3+2]*in[2] + t3[a];
                og[a] = g; sq += g * g;
            }
            const float* in2 = kp + h * (PQ * 3) + p * 3;
            float* ok = gk + (size_t)n * 144 + h * (PQ * 3) + p * 3;
#pragma unroll
            for (int a = 0; a < 3; ++a) {
                float g = R[a*3+0]*in2[0] + R[a*3+1]*in2[1] + R[a*3+2]*in2[2] + t3[a];
                ok[a] = g; sk += g * g;
            }
        }
        sqq[n * NH + h] = sq;
        sqk[n * NH + h] = sk;
        for (int p = 0; p < PV; ++p) {
            const float* in = vp + h * (PV * 3) + p * 3;
            float* og = gv + (size_t)n * 288 + h * (PV * 3) + p * 3;
#pragma unroll
            for (int a = 0; a < 3; ++a)
                og[a] = R[a*3+0]*in[0] + R[a*3+1]*in[1] + R[a*3+2]*in[2] + t3[a];
        }
    }
}

// ---------------------------------------------------------------------------
// Logits v3: grid (i=512, jt=8), block 256 (4 waves), each block does a
// 64-j tile for one i. Bias (pair@Wb) via bf16 MFMA from XOR-swizzled LDS;
// qk/cross/d2 in f32 VALU from L2. Writes pre-softmax L[i][h][j].
// ---------------------------------------------------------------------------
__global__ void logits_mfma_kernel(const float* __restrict__ pair, const float* __restrict__ proj,
                                   const float* __restrict__ gq, const float* __restrict__ gk,
                                   const float* __restrict__ sqq, const float* __restrict__ sqk,
                                   const float* __restrict__ Wb, const float* __restrict__ gamma_raw,
                                   float* __restrict__ L)
{
    __shared__ unsigned short pl[64 * 128];   // bf16, XOR-swizzled rows (16 KB)
    __shared__ float bias_s[64 * 17];         // padded to kill bank conflicts
    __shared__ float qi[192], gqi[144], sqi[12], gam[12];

    int i = blockIdx.x, jt = blockIdx.y, t = threadIdx.x;
    int lane = t & 63, w = t >> 6;

    // --- B fragments for Wb (built from L2, constant per kernel) ---
    // mfma_f32_16x16x32_bf16 B layout: lane l holds B[k = 8*(l>>4)+e][col = l&15]
    short8 bfrag[4];
    {
        int col = lane & 15;
        int kb = (lane >> 4) * 8;
#pragma unroll
        for (int ks = 0; ks < 4; ++ks) {
            short8 f;
#pragma unroll
            for (int e = 0; e < 8; ++e) {
                float v = (col < NH) ? Wb[(ks * 32 + kb + e) * NH + col] : 0.f;
                f[e] = (short)f2bf(v);
            }
            bfrag[ks] = f;
        }
    }

    // --- stage per-i small data ---
    for (int x = t; x < 192; x += 256) qi[x] = proj[(size_t)i * PRJ + x];
    for (int x = t; x < 144; x += 256) gqi[x] = gq[(size_t)i * 144 + x];
    if (t < 12) { sqi[t] = sqq[i * 12 + t]; gam[t] = softplusf(gamma_raw[t]); }

    // --- stage pair tile -> bf16 swizzled LDS ---
    const float* prow = pair + ((size_t)i * NRES + jt * 64) * CZ;
#pragma unroll
    for (int m = 0; m < 8; ++m) {
        int idx = m * 1024 + t * 4;            // element in 64x128 tile
        int row = idx >> 7, kk = idx & 127;
        float4 v = *(const float4*)&prow[idx];
        unsigned b01 = (unsigned)f2bf(v.x) | ((unsigned)f2bf(v.y) << 16);
        unsigned b23 = (unsigned)f2bf(v.z) | ((unsigned)f2bf(v.w) << 16);
        int byte = row * 256 + ((kk * 2) ^ ((row & 7) << 4));
        *(uint2*)((char*)pl + byte) = make_uint2(b01, b23);
    }
    __syncthreads();

    // --- MFMA: wave w handles j-rows [16w, 16w+16) of the tile ---
    {
        f32x4 acc = {0.f, 0.f, 0.f, 0.f};
        int arow = w * 16 + (lane & 15);
        int kb2 = (lane >> 4) * 16;            // byte offset of lane's 8-elem chunk
#pragma unroll
        for (int ks = 0; ks < 4; ++ks) {
            int byte = arow * 256 + (((ks * 64) + kb2) ^ ((arow & 7) << 4));
            short8 afrag = *(const short8*)((const char*)pl + byte);
            acc = __builtin_amdgcn_mfma_f32_16x16x32_bf16(afrag, bfrag[ks], acc, 0, 0, 0);
        }
        int crow = w * 16 + (lane >> 4) * 4;
        int ccol = lane & 15;
#pragma unroll
        for (int r = 0; r < 4; ++r) bias_s[(crow + r) * 17 + ccol] = acc[r];
    }
    __syncthreads();

    // --- f32 part: thread (j_lo = lane, hc = w) covers 3 heads ---
    const float WLc = 0.57735026918962576f;   // sqrt(1/3)
    const float WCc = 0.23570226039551584f;   // sqrt(2/(9*4))
    int j = jt * 64 + lane;
    const float* kj  = proj + (size_t)j * PRJ + 192;
    const float* gkj = gk + (size_t)j * 144;
#pragma unroll
    for (int hh = 0; hh < 3; ++hh) {
        int h = w * 3 + hh;
        float qk = 0.f;
#pragma unroll
        for (int c4 = 0; c4 < 4; ++c4) {
            float4 kv = *(const float4*)&kj[h * 16 + c4 * 4];
            const float* qh = &qi[h * 16 + c4 * 4];
            qk = fmaf(qh[0], kv.x, qk); qk = fmaf(qh[1], kv.y, qk);
            qk = fmaf(qh[2], kv.z, qk); qk = fmaf(qh[3], kv.w, qk);
        }
        float cross = 0.f;
#pragma unroll
        for (int c4 = 0; c4 < 3; ++c4) {
            float4 gv4 = *(const float4*)&gkj[h * 12 + c4 * 4];
            const float* gh = &gqi[h * 12 + c4 * 4];
            cross = fmaf(gh[0], gv4.x, cross); cross = fmaf(gh[1], gv4.y, cross);
            cross = fmaf(gh[2], gv4.z, cross); cross = fmaf(gh[3], gv4.w, cross);
        }
        float d2 = sqi[h] + sqk[(size_t)j * NH + h] - 2.f * cross;
        float logit = WLc * (qk * 0.25f + bias_s[lane * 17 + h] - 0.5f * WCc * gam[h] * d2);
        L[((size_t)i * NH + h) * NRES + j] = logit;
    }
}

// ---------------------------------------------------------------------------
// Softmax over j per (i,h) row, in place. grid = 6144, block = 256
// ---------------------------------------------------------------------------
__global__ void softmax_kernel(float* __restrict__ L)
{
    int row = blockIdx.x;
    float* p = L + (size_t)row * NRES;
    int t = threadIdx.x;
    __shared__ float red[256];
    float v0 = p[t], v1 = p[t + 256];
    red[t] = fmaxf(v0, v1);
    __syncthreads();
    for (int s = 128; s > 0; s >>= 1) { if (t < s) red[t] = fmaxf(red[t], red[t + s]); __syncthreads(); }
    float m = red[0];
    __syncthreads();
    float e0 = expf(v0 - m), e1 = expf(v1 - m);
    red[t] = e0 + e1;
    __syncthreads();
    for (int s = 128; s > 0; s >>= 1) { if (t < s) red[t] += red[t + s]; __syncthreads(); }
    float inv = 1.f / red[0];
    p[t] = e0 * inv;
    p[t + 256] = e1 * inv;
}

// ---------------------------------------------------------------------------
// o_pair: block per i, 384 threads = (32 z-quads x 12 heads)
// ---------------------------------------------------------------------------
__global__ void opair_kernel(const float* __restrict__ pair, const float* __restrict__ A,
                             float* __restrict__ concat)
{
    __shared__ float al[NH * NRES];
    int i = blockIdx.x, t = threadIdx.x;
    for (int x = t; x < NH * NRES / 4; x += 384)
        *(float4*)&al[x * 4] = *(const float4*)&A[(size_t)i * NH * NRES + x * 4];
    __syncthreads();
    int zq = t & 31, h = t >> 5;
    float4 acc = {0.f, 0.f, 0.f, 0.f};
    const float* pr = pair + (size_t)i * NRES * CZ;
    const float* ah = al + h * NRES;
    for (int j = 0; j < NRES; ++j) {
        float4 p4 = *(const float4*)&pr[(size_t)j * CZ + zq * 4];
        float a = ah[j];
        acc.x = fmaf(a, p4.x, acc.x);
        acc.y = fmaf(a, p4.y, acc.y);
        acc.z = fmaf(a, p4.z, acc.z);
        acc.w = fmaf(a, p4.w, acc.w);
    }
    *(float4*)&concat[(size_t)i * OUT_DIM + 576 + h * 128 + zq * 4] = acc;
}

// ---------------------------------------------------------------------------
// o_v, o_pt, local, norms -> concat[i, 0..575]
// ---------------------------------------------------------------------------
__global__ void ov_opt_kernel(const float* __restrict__ A, const float* __restrict__ proj,
                              const float* __restrict__ gv, const float* __restrict__ rot,
                              const float* __restrict__ trans, float* __restrict__ concat)
{
    int i = blockIdx.x, t = threadIdx.x;
    __shared__ float al[NH * NRES];
    __shared__ float opt[NH * PV * 3];
    for (int x = t; x < NH * NRES; x += 256) al[x] = A[(size_t)i * NH * NRES + x];
    __syncthreads();

    if (t < 192) {
        int h = t >> 4;
        float acc = 0.f;
        for (int j = 0; j < NRES; ++j)
            acc = fmaf(al[h * NRES + j], proj[(size_t)j * PRJ + 384 + t], acc);
        concat[(size_t)i * OUT_DIM + t] = acc;
    }
    for (int e = t; e < NH * PV * 3; e += 256) {
        int h = e / 24;
        float acc = 0.f;
        for (int j = 0; j < NRES; ++j) acc = fmaf(al[h * NRES + j], gv[(size_t)j * 288 + e], acc);
        opt[e] = acc;
    }
    __syncthreads();
    if (t < NH * PV) {
        int h = t >> 3, p = t & 7;
        float b0 = opt[h * 24 + p * 3 + 0] - trans[i * 3 + 0];
        float b1 = opt[h * 24 + p * 3 + 1] - trans[i * 3 + 1];
        float b2 = opt[h * 24 + p * 3 + 2] - trans[i * 3 + 2];
        const float* Ri = rot + i * 9;
        float l0 = Ri[0] * b0 + Ri[3] * b1 + Ri[6] * b2;
        float l1 = Ri[1] * b0 + Ri[4] * b1 + Ri[7] * b2;
        float l2 = Ri[2] * b0 + Ri[5] * b1 + Ri[8] * b2;
        float* c = concat + (size_t)i * OUT_DIM;
        c[192 + h * 24 + p * 3 + 0] = l0;
        c[192 + h * 24 + p * 3 + 1] = l1;
        c[192 + h * 24 + p * 3 + 2] = l2;
        c[480 + h * 8 + p] = sqrtf(l0 * l0 + l1 * l1 + l2 * l2 + 1e-8f);
    }
}

// ---------------------------------------------------------------------------
// LayerNorm over 384
// ---------------------------------------------------------------------------
__global__ void ln_kernel(const float* __restrict__ x, const float* __restrict__ g,
                          const float* __restrict__ b, float* __restrict__ y)
{
    int i = blockIdx.x, t = threadIdx.x;
    const float* xr = x + (size_t)i * CS;
    float a0 = xr[t], a1 = xr[t + 128], a2 = xr[t + 256];
    __shared__ float red[128];
    red[t] = a0 + a1 + a2;
    __syncthreads();
    for (int s = 64; s > 0; s >>= 1) { if (t < s) red[t] += red[t + s]; __syncthreads(); }
    float mean = red[0] * (1.f / CS);
    __syncthreads();
    float d0 = a0 - mean, d1 = a1 - mean, d2 = a2 - mean;
    red[t] = d0 * d0 + d1 * d1 + d2 * d2;
    __syncthreads();
    for (int s = 64; s > 0; s >>= 1) { if (t < s) red[t] += red[t + s]; __syncthreads(); }
    float rstd = rsqrtf(red[0] * (1.f / CS) + 1e-5f);
    float* yr = y + (size_t)i * CS;
    yr[t]       = d0 * rstd * g[t]       + b[t];
    yr[t + 128] = d1 * rstd * g[t + 128] + b[t + 128];
    yr[t + 256] = d2 * rstd * g[t + 256] + b[t + 256];
}

// ---------------------------------------------------------------------------
// Backbone update
// ---------------------------------------------------------------------------
__global__ void backbone_kernel(const float* __restrict__ sfin, const float* __restrict__ Wbu,
                                const float* __restrict__ bbu, const float* __restrict__ rot,
                                const float* __restrict__ trans, float* __restrict__ rot_out,
                                float* __restrict__ trans_out)
{
    int i = blockIdx.x * blockDim.x + threadIdx.x;
    if (i >= NRES) return;
    float u[6];
#pragma unroll
    for (int c = 0; c < 6; ++c) {
        float acc = bbu[c];
        for (int k = 0; k < CS; ++k) acc = fmaf(sfin[(size_t)i * CS + k], Wbu[k * 6 + c], acc);
        u[c] = acc;
    }
    float a = 1.f, b = u[0], c2 = u[1], d = u[2];
    float inv = rsqrtf(a * a + b * b + c2 * c2 + d * d);
    a *= inv; b *= inv; c2 *= inv; d *= inv;
    float R[9] = { a*a + b*b - c2*c2 - d*d, 2.f*(b*c2 - a*d),        2.f*(b*d + a*c2),
                   2.f*(b*c2 + a*d),        a*a - b*b + c2*c2 - d*d, 2.f*(c2*d - a*b),
                   2.f*(b*d - a*c2),        2.f*(c2*d + a*b),        a*a - b*b - c2*c2 + d*d };
    const float* Ri = rot + i * 9;
    float Rn[9];
#pragma unroll
    for (int r = 0; r < 3; ++r)
#pragma unroll
        for (int cc = 0; cc < 3; ++cc) {
            float s = 0.f;
#pragma unroll
            for (int kk = 0; kk < 3; ++kk) s += Ri[r * 3 + kk] * R[kk * 3 + cc];
            Rn[r * 3 + cc] = s;
        }
#pragma unroll
    for (int r = 0; r < 9; ++r) rot_out[i * 9 + r] = Rn[r];
    float t0 = u[3], t1 = u[4], t2 = u[5];
#pragma unroll
    for (int r = 0; r < 3; ++r)
        trans_out[i * 3 + r] = Ri[r * 3 + 0] * t0 + Ri[r * 3 + 1] * t1 + Ri[r * 3 + 2] * t2 + trans[i * 3 + r];
}

// ---------------------------------------------------------------------------
// Loss
// ---------------------------------------------------------------------------
__global__ void loss_kernel(const float* __restrict__ rot_new, const float* __restrict__ trans_new,
                            const float* __restrict__ rot_truth, const float* __restrict__ trans_truth,
                            float* __restrict__ loss)
{
    int i = blockIdx.x;
    int t = threadIdx.x;
    __shared__ float red[256];
    float Rn[9], Rt[9];
#pragma unroll
    for (int r = 0; r < 9; ++r) { Rn[r] = rot_new[i * 9 + r]; Rt[r] = rot_truth[i * 9 + r]; }
    float ti0 = trans_new[i * 3 + 0], ti1 = trans_new[i * 3 + 1], ti2 = trans_new[i * 3 + 2];
    float tt0 = trans_truth[i * 3 + 0], tt1 = trans_truth[i * 3 + 1], tt2 = trans_truth[i * 3 + 2];
    float s = 0.f;
    for (int j = t; j < NRES; j += 256) {
        float db0 = trans_new[j * 3 + 0] - ti0;
        float db1 = trans_new[j * 3 + 1] - ti1;
        float db2 = trans_new[j * 3 + 2] - ti2;
        float dp0 = Rn[0] * db0 + Rn[3] * db1 + Rn[6] * db2;
        float dp1 = Rn[1] * db0 + Rn[4] * db1 + Rn[7] * db2;
        float dp2 = Rn[2] * db0 + Rn[5] * db1 + Rn[8] * db2;
        float eb0 = trans_truth[j * 3 + 0] - tt0;
        float eb1 = trans_truth[j * 3 + 1] - tt1;
        float eb2 = trans_truth[j * 3 + 2] - tt2;
        float dt0 = Rt[0] * eb0 + Rt[3] * eb1 + Rt[6] * eb2;
        float dt1 = Rt[1] * eb0 + Rt[4] * eb1 + Rt[7] * eb2;
        float dt2 = Rt[2] * eb0 + Rt[5] * eb1 + Rt[8] * eb2;
        float dx = dp0 - dt0, dy = dp1 - dt1, dz = dp2 - dt2;
        float dd = sqrtf(dx * dx + dy * dy + dz * dz + 1e-12f);
        s += fminf(dd, 10.f);
    }
    red[t] = s;
    __syncthreads();
    for (int k = 128; k > 0; k >>= 1) { if (t < k) red[t] += red[t + k]; __syncthreads(); }
    if (t == 0) atomicAdd(loss, red[0] * (1.f / (512.f * 512.f * 10.f)));
}

// ---------------------------------------------------------------------------
extern "C" void kernel_launch(void* const* d_in, const int* in_sizes, int n_in,
                              void* d_out, int out_size, void* d_ws, size_t ws_size,
                              hipStream_t stream)
{
    const float* single      = (const float*)d_in[0];
    const float* pair        = (const float*)d_in[1];
    const float* rot         = (const float*)d_in[2];
    const float* trans       = (const float*)d_in[3];
    const float* rot_truth   = (const float*)d_in[4];
    const float* trans_truth = (const float*)d_in[5];
    const float* Wq  = (const float*)d_in[6];
    const float* Wk  = (const float*)d_in[7];
    const float* Wv  = (const float*)d_in[8];
    const float* Wqp = (const float*)d_in[9];
    const float* Wkp = (const float*)d_in[10];
    const float* Wvp = (const float*)d_in[11];
    const float* Wb  = (const float*)d_in[12];
    const float* Wo  = (const float*)d_in[13];
    const float* bo  = (const float*)d_in[14];
    const float* gamma_raw = (const float*)d_in[15];
    const float* ln1_g = (const float*)d_in[16];
    const float* ln1_b = (const float*)d_in[17];
    const float* ln2_g = (const float*)d_in[18];
    const float* ln2_b = (const float*)d_in[19];
    const float* W1 = (const float*)d_in[20];
    const float* b1 = (const float*)d_in[21];
    const float* W2 = (const float*)d_in[22];
    const float* b2 = (const float*)d_in[23];
    const float* W3 = (const float*)d_in[24];
    const float* b3 = (const float*)d_in[25];
    const float* Wbu = (const float*)d_in[26];
    const float* bbu = (const float*)d_in[27];

    float* out = (float*)d_out;
    float* single_out = out;                   // 512*384
    float* rot_out    = out + 196608;          // 512*9
    float* trans_out  = out + 201216;          // 512*3
    float* loss_out   = out + 202752;          // 1

    float* ws = (float*)d_ws;
    float* proj   = ws;                         // 512*1152 = 589824
    float* gq     = proj   + 589824;            // 73728
    float* gk     = gq     + 73728;             // 73728
    float* gv     = gk     + 73728;             // 147456
    float* sqq    = gv     + 147456;            // 6144
    float* sqk    = sqq    + 6144;              // 6144
    float* Amat   = sqk    + 6144;              // 512*12*512 = 3145728
    float* Bp     = Amat;                       // alias: used only before logits
    float* concat = Amat   + 3145728;           // 512*2112 = 1081344
    float* out1   = concat + 1081344;           // 196608
    float* sln    = out1   + 196608;            // 196608
    float* h1     = sln    + 196608;            // 196608
    float* h2     = h1     + 196608;            // 196608

    dim3 b256(256);

    // 1. pack projection weights, fused projection GEMM
    pack_proj_kernel<<<dim3((CS * PRJ + 255) / 256), b256, 0, stream>>>(Wq, Wk, Wv, Wqp, Wkp, Wvp, Bp);
    gemm_tiled<<<dim3(8, PRJ / 64, 1), b256, 0, stream>>>(single, Bp, nullptr, nullptr, proj,
                                                          NRES, CS, PRJ, 0, CS);

    // 2. frames
    frames_kernel<<<dim3(2), b256, 0, stream>>>(proj, rot, trans, gq, gk, gv, sqq, sqk);

    // 3. logits (MFMA bias) + softmax
    logits_mfma_kernel<<<dim3(NRES, 8), b256, 0, stream>>>(pair, proj, gq, gk, sqq, sqk, Wb,
                                                           gamma_raw, Amat);
    softmax_kernel<<<dim3(NRES * NH), b256, 0, stream>>>(Amat);

    // 4. attention outputs
    opair_kernel<<<dim3(NRES), dim3(384), 0, stream>>>(pair, Amat, concat);
    ov_opt_kernel<<<dim3(NRES), b256, 0, stream>>>(Amat, proj, gv, rot, trans, concat);

    // 5. ipa_out = concat @ Wo + bo + single  (k-split=4, atomic into pre-init)
    init_out1_kernel<<<dim3((NRES * CS + 255) / 256), b256, 0, stream>>>(bo, single, out1);
    gemm_tiled<<<dim3(8, CS / 64, 4), b256, 0, stream>>>(concat, Wo, nullptr, nullptr, out1,
                                                         NRES, OUT_DIM, CS, 0, 528);

    // 6. LN1 + FF + LN2
    ln_kernel<<<dim3(NRES), dim3(128), 0, stream>>>(out1, ln1_g, ln1_b, sln);
    gemm_tiled<<<dim3(8, CS / 64, 1), b256, 0, stream>>>(sln, W1, b1, nullptr, h1, NRES, CS, CS, 1, CS);
    gemm_tiled<<<dim3(8, CS / 64, 1), b256, 0, stream>>>(h1, W2, b2, nullptr, h2, NRES, CS, CS, 1, CS);
    gemm_tiled<<<dim3(8, CS / 64, 1), b256, 0, stream>>>(h2, W3, b3, sln, out1, NRES, CS, CS, 0, CS);
    ln_kernel<<<dim3(NRES), dim3(128), 0, stream>>>(out1, ln2_g, ln2_b, single_out);

    // 7. backbone + loss
    backbone_kernel<<<dim3(2), b256, 0, stream>>>(single_out, Wbu, bbu, rot, trans, rot_out, trans_out);
    hipMemsetAsync(loss_out, 0, sizeof(float), stream);
    loss_kernel<<<dim3(NRES), b256, 0, stream>>>(rot_out, trans_out, rot_truth, trans_truth, loss_out);
}

// Round 4
// 382.802 us; speedup vs baseline: 2.1175x; 1.4381x over previous
//
#include <hip/hip_runtime.h>
#include <hip/hip_bf16.h>
#include <math.h>

#define NRES 512
#define CS 384
#define CZ 128
#define NH 12
#define PQ 4
#define PV 8
#define OUT_DIM 2112   // H*(C + 3*PV + PV + CZ)
#define PRJ 1152       // packed projection width: q192|k192|v192|qp144|kp144|vp288

typedef __attribute__((ext_vector_type(8))) short short8;
typedef __attribute__((ext_vector_type(4))) float f32x4;

__device__ __forceinline__ float softplusf(float x) { return log1pf(expf(x)); }

__device__ __forceinline__ unsigned short f2bf(float f) {
    union { float f; unsigned u; } v; v.f = f;
    unsigned r = v.u + 0x7FFF + ((v.u >> 16) & 1);
    return (unsigned short)(r >> 16);
}

// ---------------------------------------------------------------------------
// Pack 6 projection weight matrices into Bp[384][1152]
// ---------------------------------------------------------------------------
__global__ void pack_proj_kernel(const float* __restrict__ Wq, const float* __restrict__ Wk,
                                 const float* __restrict__ Wv, const float* __restrict__ Wqp,
                                 const float* __restrict__ Wkp, const float* __restrict__ Wvp,
                                 float* __restrict__ Bp)
{
    int x = blockIdx.x * blockDim.x + threadIdx.x;
    if (x >= CS * PRJ) return;
    int k = x / PRJ, c = x % PRJ;
    float v;
    if      (c < 192)  v = Wq [k * 192 + c];
    else if (c < 384)  v = Wk [k * 192 + (c - 192)];
    else if (c < 576)  v = Wv [k * 192 + (c - 384)];
    else if (c < 720)  v = Wqp[k * 144 + (c - 576)];
    else if (c < 864)  v = Wkp[k * 144 + (c - 720)];
    else               v = Wvp[k * 288 + (c - 864)];
    Bp[x] = v;
}

// ---------------------------------------------------------------------------
// Tiled f32 GEMM: BM=64, BN=64, BK=16, 256 threads, 4x4 micro-tile.
// If gridDim.z > 1: k-split partial, atomicAdd into pre-initialized C.
// ---------------------------------------------------------------------------
__global__ void gemm_tiled(const float* __restrict__ A, const float* __restrict__ B,
                           const float* __restrict__ bias, const float* __restrict__ res,
                           float* __restrict__ C, int M, int K, int Nc, int relu, int KS)
{
    __shared__ float As[16][68];
    __shared__ float Bs[16][64];
    int m0 = blockIdx.x * 64, n0 = blockIdx.y * 64;
    int kbeg = blockIdx.z * KS;
    int t = threadIdx.x;
    int tm = t >> 4, tn = t & 15;
    int lr = t >> 2, lc4 = t & 3;
    int br = t >> 4, bc4 = t & 15;
    float acc[4][4] = {{0.f}};

    for (int kt = kbeg; kt < kbeg + KS; kt += 16) {
        float4 a4 = *(const float4*)&A[(size_t)(m0 + lr) * K + kt + lc4 * 4];
        float4 b4 = *(const float4*)&B[(size_t)(kt + br) * Nc + n0 + bc4 * 4];
        As[lc4 * 4 + 0][lr] = a4.x;
        As[lc4 * 4 + 1][lr] = a4.y;
        As[lc4 * 4 + 2][lr] = a4.z;
        As[lc4 * 4 + 3][lr] = a4.w;
        *(float4*)&Bs[br][bc4 * 4] = b4;
        __syncthreads();
#pragma unroll
        for (int k = 0; k < 16; ++k) {
            float4 av = *(const float4*)&As[k][tm * 4];
            float4 bv = *(const float4*)&Bs[k][tn * 4];
            acc[0][0] = fmaf(av.x, bv.x, acc[0][0]); acc[0][1] = fmaf(av.x, bv.y, acc[0][1]);
            acc[0][2] = fmaf(av.x, bv.z, acc[0][2]); acc[0][3] = fmaf(av.x, bv.w, acc[0][3]);
            acc[1][0] = fmaf(av.y, bv.x, acc[1][0]); acc[1][1] = fmaf(av.y, bv.y, acc[1][1]);
            acc[1][2] = fmaf(av.y, bv.z, acc[1][2]); acc[1][3] = fmaf(av.y, bv.w, acc[1][3]);
            acc[2][0] = fmaf(av.z, bv.x, acc[2][0]); acc[2][1] = fmaf(av.z, bv.y, acc[2][1]);
            acc[2][2] = fmaf(av.z, bv.z, acc[2][2]); acc[2][3] = fmaf(av.z, bv.w, acc[2][3]);
            acc[3][0] = fmaf(av.w, bv.x, acc[3][0]); acc[3][1] = fmaf(av.w, bv.y, acc[3][1]);
            acc[3][2] = fmaf(av.w, bv.z, acc[3][2]); acc[3][3] = fmaf(av.w, bv.w, acc[3][3]);
        }
        __syncthreads();
    }

    if (gridDim.z > 1) {
#pragma unroll
        for (int r = 0; r < 4; ++r)
#pragma unroll
            for (int c = 0; c < 4; ++c)
                atomicAdd(&C[(size_t)(m0 + tm * 4 + r) * Nc + n0 + tn * 4 + c], acc[r][c]);
    } else {
#pragma unroll
        for (int r = 0; r < 4; ++r) {
            int row = m0 + tm * 4 + r;
            float4 v;
            float* vp = (float*)&v;
#pragma unroll
            for (int c = 0; c < 4; ++c) {
                int col = n0 + tn * 4 + c;
                float x = acc[r][c];
                if (bias) x += bias[col];
                if (res)  x += res[(size_t)row * Nc + col];
                if (relu) x = fmaxf(x, 0.f);
                vp[c] = x;
            }
            *(float4*)&C[(size_t)row * Nc + n0 + tn * 4] = v;
        }
    }
}

// ---------------------------------------------------------------------------
__global__ void init_out1_kernel(const float* __restrict__ bo, const float* __restrict__ single,
                                 float* __restrict__ out1)
{
    int x = blockIdx.x * blockDim.x + threadIdx.x;
    if (x >= NRES * CS) return;
    out1[x] = bo[x % CS] + single[x];
}

// ---------------------------------------------------------------------------
// Frames v2: one thread per (n, h). grid = 24 blocks of 256.
// ---------------------------------------------------------------------------
__global__ void frames_kernel(const float* __restrict__ proj, const float* __restrict__ rot,
                              const float* __restrict__ trans,
                              float* __restrict__ gq, float* __restrict__ gk,
                              float* __restrict__ gv, float* __restrict__ sqq,
                              float* __restrict__ sqk)
{
    int x = blockIdx.x * blockDim.x + threadIdx.x;
    if (x >= NRES * NH) return;
    int n = x / NH, h = x % NH;
    float R[9], t3[3];
#pragma unroll
    for (int r = 0; r < 9; ++r) R[r] = rot[n * 9 + r];
#pragma unroll
    for (int r = 0; r < 3; ++r) t3[r] = trans[n * 3 + r];
    const float* qp = proj + (size_t)n * PRJ + 576 + h * (PQ * 3);
    const float* kp = proj + (size_t)n * PRJ + 720 + h * (PQ * 3);
    const float* vp = proj + (size_t)n * PRJ + 864 + h * (PV * 3);

    float sq = 0.f, sk = 0.f;
#pragma unroll
    for (int p = 0; p < PQ; ++p) {
        const float* in = qp + p * 3;
        float* og = gq + (size_t)n * 144 + h * (PQ * 3) + p * 3;
#pragma unroll
        for (int a = 0; a < 3; ++a) {
            float g = R[a*3+0]*in[0] + R[a*3+1]*in[1] + R[a*3+2]*in[2] + t3[a];
            og[a] = g; sq += g * g;
        }
        const float* in2 = kp + p * 3;
        float* ok = gk + (size_t)n * 144 + h * (PQ * 3) + p * 3;
#pragma unroll
        for (int a = 0; a < 3; ++a) {
            float g = R[a*3+0]*in2[0] + R[a*3+1]*in2[1] + R[a*3+2]*in2[2] + t3[a];
            ok[a] = g; sk += g * g;
        }
    }
    sqq[n * NH + h] = sq;
    sqk[n * NH + h] = sk;
#pragma unroll
    for (int p = 0; p < PV; ++p) {
        const float* in = vp + p * 3;
        float* og = gv + (size_t)n * 288 + h * (PV * 3) + p * 3;
#pragma unroll
        for (int a = 0; a < 3; ++a)
            og[a] = R[a*3+0]*in[0] + R[a*3+1]*in[1] + R[a*3+2]*in[2] + t3[a];
    }
}

// ---------------------------------------------------------------------------
// Logits v3: grid (i=512, jt=8), block 256 (4 waves). Bias via bf16 MFMA.
// ---------------------------------------------------------------------------
__global__ void logits_mfma_kernel(const float* __restrict__ pair, const float* __restrict__ proj,
                                   const float* __restrict__ gq, const float* __restrict__ gk,
                                   const float* __restrict__ sqq, const float* __restrict__ sqk,
                                   const float* __restrict__ Wb, const float* __restrict__ gamma_raw,
                                   float* __restrict__ L)
{
    __shared__ unsigned short pl[64 * 128];   // bf16, XOR-swizzled rows (16 KB)
    __shared__ float bias_s[64 * 17];
    __shared__ float qi[192], gqi[144], sqi[12], gam[12];

    int i = blockIdx.x, jt = blockIdx.y, t = threadIdx.x;
    int lane = t & 63, w = t >> 6;

    short8 bfrag[4];
    {
        int col = lane & 15;
        int kb = (lane >> 4) * 8;
#pragma unroll
        for (int ks = 0; ks < 4; ++ks) {
            short8 f;
#pragma unroll
            for (int e = 0; e < 8; ++e) {
                float v = (col < NH) ? Wb[(ks * 32 + kb + e) * NH + col] : 0.f;
                f[e] = (short)f2bf(v);
            }
            bfrag[ks] = f;
        }
    }

    for (int x = t; x < 192; x += 256) qi[x] = proj[(size_t)i * PRJ + x];
    for (int x = t; x < 144; x += 256) gqi[x] = gq[(size_t)i * 144 + x];
    if (t < 12) { sqi[t] = sqq[i * 12 + t]; gam[t] = softplusf(gamma_raw[t]); }

    const float* prow = pair + ((size_t)i * NRES + jt * 64) * CZ;
#pragma unroll
    for (int m = 0; m < 8; ++m) {
        int idx = m * 1024 + t * 4;
        int row = idx >> 7, kk = idx & 127;
        float4 v = *(const float4*)&prow[idx];
        unsigned b01 = (unsigned)f2bf(v.x) | ((unsigned)f2bf(v.y) << 16);
        unsigned b23 = (unsigned)f2bf(v.z) | ((unsigned)f2bf(v.w) << 16);
        int byte = row * 256 + ((kk * 2) ^ ((row & 7) << 4));
        *(uint2*)((char*)pl + byte) = make_uint2(b01, b23);
    }
    __syncthreads();

    {
        f32x4 acc = {0.f, 0.f, 0.f, 0.f};
        int arow = w * 16 + (lane & 15);
        int kb2 = (lane >> 4) * 16;
#pragma unroll
        for (int ks = 0; ks < 4; ++ks) {
            int byte = arow * 256 + (((ks * 64) + kb2) ^ ((arow & 7) << 4));
            short8 afrag = *(const short8*)((const char*)pl + byte);
            acc = __builtin_amdgcn_mfma_f32_16x16x32_bf16(afrag, bfrag[ks], acc, 0, 0, 0);
        }
        int crow = w * 16 + (lane >> 4) * 4;
        int ccol = lane & 15;
#pragma unroll
        for (int r = 0; r < 4; ++r) bias_s[(crow + r) * 17 + ccol] = acc[r];
    }
    __syncthreads();

    const float WLc = 0.57735026918962576f;
    const float WCc = 0.23570226039551584f;
    int j = jt * 64 + lane;
    const float* kj  = proj + (size_t)j * PRJ + 192;
    const float* gkj = gk + (size_t)j * 144;
#pragma unroll
    for (int hh = 0; hh < 3; ++hh) {
        int h = w * 3 + hh;
        float qk = 0.f;
#pragma unroll
        for (int c4 = 0; c4 < 4; ++c4) {
            float4 kv = *(const float4*)&kj[h * 16 + c4 * 4];
            const float* qh = &qi[h * 16 + c4 * 4];
            qk = fmaf(qh[0], kv.x, qk); qk = fmaf(qh[1], kv.y, qk);
            qk = fmaf(qh[2], kv.z, qk); qk = fmaf(qh[3], kv.w, qk);
        }
        float cross = 0.f;
#pragma unroll
        for (int c4 = 0; c4 < 3; ++c4) {
            float4 gv4 = *(const float4*)&gkj[h * 12 + c4 * 4];
            const float* gh = &gqi[h * 12 + c4 * 4];
            cross = fmaf(gh[0], gv4.x, cross); cross = fmaf(gh[1], gv4.y, cross);
            cross = fmaf(gh[2], gv4.z, cross); cross = fmaf(gh[3], gv4.w, cross);
        }
        float d2 = sqi[h] + sqk[(size_t)j * NH + h] - 2.f * cross;
        float logit = WLc * (qk * 0.25f + bias_s[lane * 17 + h] - 0.5f * WCc * gam[h] * d2);
        L[((size_t)i * NH + h) * NRES + j] = logit;
    }
}

// ---------------------------------------------------------------------------
// Softmax over j per (i,h) row, in place. grid = 6144, block = 256
// ---------------------------------------------------------------------------
__global__ void softmax_kernel(float* __restrict__ L)
{
    int row = blockIdx.x;
    float* p = L + (size_t)row * NRES;
    int t = threadIdx.x;
    __shared__ float red[256];
    float v0 = p[t], v1 = p[t + 256];
    red[t] = fmaxf(v0, v1);
    __syncthreads();
    for (int s = 128; s > 0; s >>= 1) { if (t < s) red[t] = fmaxf(red[t], red[t + s]); __syncthreads(); }
    float m = red[0];
    __syncthreads();
    float e0 = expf(v0 - m), e1 = expf(v1 - m);
    red[t] = e0 + e1;
    __syncthreads();
    for (int s = 128; s > 0; s >>= 1) { if (t < s) red[t] += red[t + s]; __syncthreads(); }
    float inv = 1.f / red[0];
    p[t] = e0 * inv;
    p[t + 256] = e1 * inv;
}

// ---------------------------------------------------------------------------
// o_pair: block per i, 384 threads = (32 z-quads x 12 heads)
// ---------------------------------------------------------------------------
__global__ void opair_kernel(const float* __restrict__ pair, const float* __restrict__ A,
                             float* __restrict__ concat)
{
    __shared__ float al[NH * NRES];
    int i = blockIdx.x, t = threadIdx.x;
    for (int x = t; x < NH * NRES / 4; x += 384)
        *(float4*)&al[x * 4] = *(const float4*)&A[(size_t)i * NH * NRES + x * 4];
    __syncthreads();
    int zq = t & 31, h = t >> 5;
    float4 acc = {0.f, 0.f, 0.f, 0.f};
    const float* pr = pair + (size_t)i * NRES * CZ;
    const float* ah = al + h * NRES;
    for (int j = 0; j < NRES; ++j) {
        float4 p4 = *(const float4*)&pr[(size_t)j * CZ + zq * 4];
        float a = ah[j];
        acc.x = fmaf(a, p4.x, acc.x);
        acc.y = fmaf(a, p4.y, acc.y);
        acc.z = fmaf(a, p4.z, acc.z);
        acc.w = fmaf(a, p4.w, acc.w);
    }
    *(float4*)&concat[(size_t)i * OUT_DIM + 576 + h * 128 + zq * 4] = acc;
}

// ---------------------------------------------------------------------------
// o_v, o_pt, local, norms -> concat[i, 0..575]
// ---------------------------------------------------------------------------
__global__ void ov_opt_kernel(const float* __restrict__ A, const float* __restrict__ proj,
                              const float* __restrict__ gv, const float* __restrict__ rot,
                              const float* __restrict__ trans, float* __restrict__ concat)
{
    int i = blockIdx.x, t = threadIdx.x;
    __shared__ float al[NH * NRES];
    __shared__ float opt[NH * PV * 3];
    for (int x = t; x < NH * NRES; x += 256) al[x] = A[(size_t)i * NH * NRES + x];
    __syncthreads();

    if (t < 192) {
        int h = t >> 4;
        float acc = 0.f;
        for (int j = 0; j < NRES; ++j)
            acc = fmaf(al[h * NRES + j], proj[(size_t)j * PRJ + 384 + t], acc);
        concat[(size_t)i * OUT_DIM + t] = acc;
    }
    for (int e = t; e < NH * PV * 3; e += 256) {
        int h = e / 24;
        float acc = 0.f;
        for (int j = 0; j < NRES; ++j) acc = fmaf(al[h * NRES + j], gv[(size_t)j * 288 + e], acc);
        opt[e] = acc;
    }
    __syncthreads();
    if (t < NH * PV) {
        int h = t >> 3, p = t & 7;
        float b0 = opt[h * 24 + p * 3 + 0] - trans[i * 3 + 0];
        float b1 = opt[h * 24 + p * 3 + 1] - trans[i * 3 + 1];
        float b2 = opt[h * 24 + p * 3 + 2] - trans[i * 3 + 2];
        const float* Ri = rot + i * 9;
        float l0 = Ri[0] * b0 + Ri[3] * b1 + Ri[6] * b2;
        float l1 = Ri[1] * b0 + Ri[4] * b1 + Ri[7] * b2;
        float l2 = Ri[2] * b0 + Ri[5] * b1 + Ri[8] * b2;
        float* c = concat + (size_t)i * OUT_DIM;
        c[192 + h * 24 + p * 3 + 0] = l0;
        c[192 + h * 24 + p * 3 + 1] = l1;
        c[192 + h * 24 + p * 3 + 2] = l2;
        c[480 + h * 8 + p] = sqrtf(l0 * l0 + l1 * l1 + l2 * l2 + 1e-8f);
    }
}

// ---------------------------------------------------------------------------
// LayerNorm over 384
// ---------------------------------------------------------------------------
__global__ void ln_kernel(const float* __restrict__ x, const float* __restrict__ g,
                          const float* __restrict__ b, float* __restrict__ y)
{
    int i = blockIdx.x, t = threadIdx.x;
    const float* xr = x + (size_t)i * CS;
    float a0 = xr[t], a1 = xr[t + 128], a2 = xr[t + 256];
    __shared__ float red[128];
    red[t] = a0 + a1 + a2;
    __syncthreads();
    for (int s = 64; s > 0; s >>= 1) { if (t < s) red[t] += red[t + s]; __syncthreads(); }
    float mean = red[0] * (1.f / CS);
    __syncthreads();
    float d0 = a0 - mean, d1 = a1 - mean, d2 = a2 - mean;
    red[t] = d0 * d0 + d1 * d1 + d2 * d2;
    __syncthreads();
    for (int s = 64; s > 0; s >>= 1) { if (t < s) red[t] += red[t + s]; __syncthreads(); }
    float rstd = rsqrtf(red[0] * (1.f / CS) + 1e-5f);
    float* yr = y + (size_t)i * CS;
    yr[t]       = d0 * rstd * g[t]       + b[t];
    yr[t + 128] = d1 * rstd * g[t + 128] + b[t + 128];
    yr[t + 256] = d2 * rstd * g[t + 256] + b[t + 256];
}

// ---------------------------------------------------------------------------
// Backbone v2: one block (128 thr) per residue; LDS reduce over 6 comps.
// ---------------------------------------------------------------------------
__global__ void backbone_kernel(const float* __restrict__ sfin, const float* __restrict__ Wbu,
                                const float* __restrict__ bbu, const float* __restrict__ rot,
                                const float* __restrict__ trans, float* __restrict__ rot_out,
                                float* __restrict__ trans_out)
{
    int i = blockIdx.x, t = threadIdx.x;
    float part[6] = {0.f, 0.f, 0.f, 0.f, 0.f, 0.f};
    for (int k = t; k < CS; k += 128) {
        float s = sfin[(size_t)i * CS + k];
        const float* wr = Wbu + k * 6;
#pragma unroll
        for (int c = 0; c < 6; ++c) part[c] = fmaf(s, wr[c], part[c]);
    }
    __shared__ float red[6][128];
#pragma unroll
    for (int c = 0; c < 6; ++c) red[c][t] = part[c];
    __syncthreads();
    for (int s = 64; s > 0; s >>= 1) {
        if (t < s) {
#pragma unroll
            for (int c = 0; c < 6; ++c) red[c][t] += red[c][t + s];
        }
        __syncthreads();
    }
    if (t == 0) {
        float u[6];
#pragma unroll
        for (int c = 0; c < 6; ++c) u[c] = red[c][0] + bbu[c];
        float a = 1.f, b = u[0], c2 = u[1], d = u[2];
        float inv = rsqrtf(a * a + b * b + c2 * c2 + d * d);
        a *= inv; b *= inv; c2 *= inv; d *= inv;
        float R[9] = { a*a + b*b - c2*c2 - d*d, 2.f*(b*c2 - a*d),        2.f*(b*d + a*c2),
                       2.f*(b*c2 + a*d),        a*a - b*b + c2*c2 - d*d, 2.f*(c2*d - a*b),
                       2.f*(b*d - a*c2),        2.f*(c2*d + a*b),        a*a - b*b - c2*c2 + d*d };
        const float* Ri = rot + i * 9;
        float Rn[9];
#pragma unroll
        for (int r = 0; r < 3; ++r)
#pragma unroll
            for (int cc = 0; cc < 3; ++cc) {
                float s2 = 0.f;
#pragma unroll
                for (int kk = 0; kk < 3; ++kk) s2 += Ri[r * 3 + kk] * R[kk * 3 + cc];
                Rn[r * 3 + cc] = s2;
            }
#pragma unroll
        for (int r = 0; r < 9; ++r) rot_out[i * 9 + r] = Rn[r];
        float t0 = u[3], t1 = u[4], t2 = u[5];
#pragma unroll
        for (int r = 0; r < 3; ++r)
            trans_out[i * 3 + r] = Ri[r * 3 + 0] * t0 + Ri[r * 3 + 1] * t1 + Ri[r * 3 + 2] * t2 + trans[i * 3 + r];
    }
}

// ---------------------------------------------------------------------------
// Loss
// ---------------------------------------------------------------------------
__global__ void loss_kernel(const float* __restrict__ rot_new, const float* __restrict__ trans_new,
                            const float* __restrict__ rot_truth, const float* __restrict__ trans_truth,
                            float* __restrict__ loss)
{
    int i = blockIdx.x;
    int t = threadIdx.x;
    __shared__ float red[256];
    float Rn[9], Rt[9];
#pragma unroll
    for (int r = 0; r < 9; ++r) { Rn[r] = rot_new[i * 9 + r]; Rt[r] = rot_truth[i * 9 + r]; }
    float ti0 = trans_new[i * 3 + 0], ti1 = trans_new[i * 3 + 1], ti2 = trans_new[i * 3 + 2];
    float tt0 = trans_truth[i * 3 + 0], tt1 = trans_truth[i * 3 + 1], tt2 = trans_truth[i * 3 + 2];
    float s = 0.f;
    for (int j = t; j < NRES; j += 256) {
        float db0 = trans_new[j * 3 + 0] - ti0;
        float db1 = trans_new[j * 3 + 1] - ti1;
        float db2 = trans_new[j * 3 + 2] - ti2;
        float dp0 = Rn[0] * db0 + Rn[3] * db1 + Rn[6] * db2;
        float dp1 = Rn[1] * db0 + Rn[4] * db1 + Rn[7] * db2;
        float dp2 = Rn[2] * db0 + Rn[5] * db1 + Rn[8] * db2;
        float eb0 = trans_truth[j * 3 + 0] - tt0;
        float eb1 = trans_truth[j * 3 + 1] - tt1;
        float eb2 = trans_truth[j * 3 + 2] - tt2;
        float dt0 = Rt[0] * eb0 + Rt[3] * eb1 + Rt[6] * eb2;
        float dt1 = Rt[1] * eb0 + Rt[4] * eb1 + Rt[7] * eb2;
        float dt2 = Rt[2] * eb0 + Rt[5] * eb1 + Rt[8] * eb2;
        float dx = dp0 - dt0, dy = dp1 - dt1, dz = dp2 - dt2;
        float dd = sqrtf(dx * dx + dy * dy + dz * dz + 1e-12f);
        s += fminf(dd, 10.f);
    }
    red[t] = s;
    __syncthreads();
    for (int k = 128; k > 0; k >>= 1) { if (t < k) red[t] += red[t + k]; __syncthreads(); }
    if (t == 0) atomicAdd(loss, red[0] * (1.f / (512.f * 512.f * 10.f)));
}

// ---------------------------------------------------------------------------
extern "C" void kernel_launch(void* const* d_in, const int* in_sizes, int n_in,
                              void* d_out, int out_size, void* d_ws, size_t ws_size,
                              hipStream_t stream)
{
    const float* single      = (const float*)d_in[0];
    const float* pair        = (const float*)d_in[1];
    const float* rot         = (const float*)d_in[2];
    const float* trans       = (const float*)d_in[3];
    const float* rot_truth   = (const float*)d_in[4];
    const float* trans_truth = (const float*)d_in[5];
    const float* Wq  = (const float*)d_in[6];
    const float* Wk  = (const float*)d_in[7];
    const float* Wv  = (const float*)d_in[8];
    const float* Wqp = (const float*)d_in[9];
    const float* Wkp = (const float*)d_in[10];
    const float* Wvp = (const float*)d_in[11];
    const float* Wb  = (const float*)d_in[12];
    const float* Wo  = (const float*)d_in[13];
    const float* bo  = (const float*)d_in[14];
    const float* gamma_raw = (const float*)d_in[15];
    const float* ln1_g = (const float*)d_in[16];
    const float* ln1_b = (const float*)d_in[17];
    const float* ln2_g = (const float*)d_in[18];
    const float* ln2_b = (const float*)d_in[19];
    const float* W1 = (const float*)d_in[20];
    const float* b1 = (const float*)d_in[21];
    const float* W2 = (const float*)d_in[22];
    const float* b2 = (const float*)d_in[23];
    const float* W3 = (const float*)d_in[24];
    const float* b3 = (const float*)d_in[25];
    const float* Wbu = (const float*)d_in[26];
    const float* bbu = (const float*)d_in[27];

    float* out = (float*)d_out;
    float* single_out = out;                   // 512*384
    float* rot_out    = out + 196608;          // 512*9
    float* trans_out  = out + 201216;          // 512*3
    float* loss_out   = out + 202752;          // 1

    float* ws = (float*)d_ws;
    float* proj   = ws;                         // 512*1152 = 589824
    float* gq     = proj   + 589824;            // 73728
    float* gk     = gq     + 73728;             // 73728
    float* gv     = gk     + 73728;             // 147456
    float* sqq    = gv     + 147456;            // 6144
    float* sqk    = sqq    + 6144;              // 6144
    float* Amat   = sqk    + 6144;              // 512*12*512 = 3145728
    float* Bp     = Amat;                       // alias: used only before logits
    float* concat = Amat   + 3145728;           // 512*2112 = 1081344
    float* out1   = concat + 1081344;           // 196608
    float* sln    = out1   + 196608;            // 196608
    float* h1     = sln    + 196608;            // 196608
    float* h2     = h1     + 196608;            // 196608

    dim3 b256(256);

    // 1. pack projection weights, fused projection GEMM
    pack_proj_kernel<<<dim3((CS * PRJ + 255) / 256), b256, 0, stream>>>(Wq, Wk, Wv, Wqp, Wkp, Wvp, Bp);
    gemm_tiled<<<dim3(8, PRJ / 64, 1), b256, 0, stream>>>(single, Bp, nullptr, nullptr, proj,
                                                          NRES, CS, PRJ, 0, CS);

    // 2. frames (one thread per (n,h))
    frames_kernel<<<dim3((NRES * NH + 255) / 256), b256, 0, stream>>>(proj, rot, trans, gq, gk, gv, sqq, sqk);

    // 3. logits (MFMA bias) + softmax
    logits_mfma_kernel<<<dim3(NRES, 8), b256, 0, stream>>>(pair, proj, gq, gk, sqq, sqk, Wb,
                                                           gamma_raw, Amat);
    softmax_kernel<<<dim3(NRES * NH), b256, 0, stream>>>(Amat);

    // 4. attention outputs
    opair_kernel<<<dim3(NRES), dim3(384), 0, stream>>>(pair, Amat, concat);
    ov_opt_kernel<<<dim3(NRES), b256, 0, stream>>>(Amat, proj, gv, rot, trans, concat);

    // 5. ipa_out = concat @ Wo + bo + single  (k-split=4, atomic into pre-init)
    init_out1_kernel<<<dim3((NRES * CS + 255) / 256), b256, 0, stream>>>(bo, single, out1);
    gemm_tiled<<<dim3(8, CS / 64, 4), b256, 0, stream>>>(concat, Wo, nullptr, nullptr, out1,
                                                         NRES, OUT_DIM, CS, 0, 528);

    // 6. LN1 + FF + LN2
    ln_kernel<<<dim3(NRES), dim3(128), 0, stream>>>(out1, ln1_g, ln1_b, sln);
    gemm_tiled<<<dim3(8, CS / 64, 1), b256, 0, stream>>>(sln, W1, b1, nullptr, h1, NRES, CS, CS, 1, CS);
    gemm_tiled<<<dim3(8, CS / 64, 1), b256, 0, stream>>>(h1, W2, b2, nullptr, h2, NRES, CS, CS, 1, CS);
    gemm_tiled<<<dim3(8, CS / 64, 1), b256, 0, stream>>>(h2, W3, b3, sln, out1, NRES, CS, CS, 0, CS);
    ln_kernel<<<dim3(NRES), dim3(128), 0, stream>>>(out1, ln2_g, ln2_b, single_out);

    // 7. backbone (block per residue) + loss
    backbone_kernel<<<dim3(NRES), dim3(128), 0, stream>>>(single_out, Wbu, bbu, rot, trans, rot_out, trans_out);
    hipMemsetAsync(loss_out, 0, sizeof(float), stream);
    loss_kernel<<<dim3(NRES), b256, 0, stream>>>(rot_out, trans_out, rot_truth, trans_truth, loss_out);
}

// Round 5
// 354.634 us; speedup vs baseline: 2.2857x; 1.0794x over previous
//
#include <hip/hip_runtime.h>
#include <hip/hip_bf16.h>
#include <math.h>

#define NRES 512
#define CS 384
#define CZ 128
#define NH 12
#define PQ 4
#define PV 8
#define OUT_DIM 2112   // H*(C + 3*PV + PV + CZ)
#define PRJ 1152       // packed projection width: q192|k192|v192|qp144|kp144|vp288

typedef __attribute__((ext_vector_type(8))) short short8;
typedef __attribute__((ext_vector_type(4))) float f32x4;

__device__ __forceinline__ float softplusf(float x) { return log1pf(expf(x)); }

__device__ __forceinline__ unsigned short f2bf(float f) {
    union { float f; unsigned u; } v; v.f = f;
    unsigned r = v.u + 0x7FFF + ((v.u >> 16) & 1);
    return (unsigned short)(r >> 16);
}

// ---------------------------------------------------------------------------
// Pack 6 projection weight matrices into Bp[384][1152]
// ---------------------------------------------------------------------------
__global__ void pack_proj_kernel(const float* __restrict__ Wq, const float* __restrict__ Wk,
                                 const float* __restrict__ Wv, const float* __restrict__ Wqp,
                                 const float* __restrict__ Wkp, const float* __restrict__ Wvp,
                                 float* __restrict__ Bp)
{
    int x = blockIdx.x * blockDim.x + threadIdx.x;
    if (x >= CS * PRJ) return;
    int k = x / PRJ, c = x % PRJ;
    float v;
    if      (c < 192)  v = Wq [k * 192 + c];
    else if (c < 384)  v = Wk [k * 192 + (c - 192)];
    else if (c < 576)  v = Wv [k * 192 + (c - 384)];
    else if (c < 720)  v = Wqp[k * 144 + (c - 576)];
    else if (c < 864)  v = Wkp[k * 144 + (c - 720)];
    else               v = Wvp[k * 288 + (c - 864)];
    Bp[x] = v;
}

// ---------------------------------------------------------------------------
// Tiled f32 GEMM: BM=64, BN=64, BK=16, 256 threads, 4x4 micro-tile.
// If gridDim.z > 1: k-split partial, atomicAdd into pre-initialized C.
// ---------------------------------------------------------------------------
__global__ void gemm_tiled(const float* __restrict__ A, const float* __restrict__ B,
                           const float* __restrict__ bias, const float* __restrict__ res,
                           float* __restrict__ C, int M, int K, int Nc, int relu, int KS)
{
    __shared__ float As[16][68];
    __shared__ float Bs[16][64];
    int m0 = blockIdx.x * 64, n0 = blockIdx.y * 64;
    int kbeg = blockIdx.z * KS;
    int t = threadIdx.x;
    int tm = t >> 4, tn = t & 15;
    int lr = t >> 2, lc4 = t & 3;
    int br = t >> 4, bc4 = t & 15;
    float acc[4][4] = {{0.f}};

    for (int kt = kbeg; kt < kbeg + KS; kt += 16) {
        float4 a4 = *(const float4*)&A[(size_t)(m0 + lr) * K + kt + lc4 * 4];
        float4 b4 = *(const float4*)&B[(size_t)(kt + br) * Nc + n0 + bc4 * 4];
        As[lc4 * 4 + 0][lr] = a4.x;
        As[lc4 * 4 + 1][lr] = a4.y;
        As[lc4 * 4 + 2][lr] = a4.z;
        As[lc4 * 4 + 3][lr] = a4.w;
        *(float4*)&Bs[br][bc4 * 4] = b4;
        __syncthreads();
#pragma unroll
        for (int k = 0; k < 16; ++k) {
            float4 av = *(const float4*)&As[k][tm * 4];
            float4 bv = *(const float4*)&Bs[k][tn * 4];
            acc[0][0] = fmaf(av.x, bv.x, acc[0][0]); acc[0][1] = fmaf(av.x, bv.y, acc[0][1]);
            acc[0][2] = fmaf(av.x, bv.z, acc[0][2]); acc[0][3] = fmaf(av.x, bv.w, acc[0][3]);
            acc[1][0] = fmaf(av.y, bv.x, acc[1][0]); acc[1][1] = fmaf(av.y, bv.y, acc[1][1]);
            acc[1][2] = fmaf(av.y, bv.z, acc[1][2]); acc[1][3] = fmaf(av.y, bv.w, acc[1][3]);
            acc[2][0] = fmaf(av.z, bv.x, acc[2][0]); acc[2][1] = fmaf(av.z, bv.y, acc[2][1]);
            acc[2][2] = fmaf(av.z, bv.z, acc[2][2]); acc[2][3] = fmaf(av.z, bv.w, acc[2][3]);
            acc[3][0] = fmaf(av.w, bv.x, acc[3][0]); acc[3][1] = fmaf(av.w, bv.y, acc[3][1]);
            acc[3][2] = fmaf(av.w, bv.z, acc[3][2]); acc[3][3] = fmaf(av.w, bv.w, acc[3][3]);
        }
        __syncthreads();
    }

    if (gridDim.z > 1) {
#pragma unroll
        for (int r = 0; r < 4; ++r)
#pragma unroll
            for (int c = 0; c < 4; ++c)
                atomicAdd(&C[(size_t)(m0 + tm * 4 + r) * Nc + n0 + tn * 4 + c], acc[r][c]);
    } else {
#pragma unroll
        for (int r = 0; r < 4; ++r) {
            int row = m0 + tm * 4 + r;
            float4 v;
            float* vp = (float*)&v;
#pragma unroll
            for (int c = 0; c < 4; ++c) {
                int col = n0 + tn * 4 + c;
                float x = acc[r][c];
                if (bias) x += bias[col];
                if (res)  x += res[(size_t)row * Nc + col];
                if (relu) x = fmaxf(x, 0.f);
                vp[c] = x;
            }
            *(float4*)&C[(size_t)row * Nc + n0 + tn * 4] = v;
        }
    }
}

// ---------------------------------------------------------------------------
__global__ void init_out1_kernel(const float* __restrict__ bo, const float* __restrict__ single,
                                 float* __restrict__ out1)
{
    int x = blockIdx.x * blockDim.x + threadIdx.x;
    if (x >= NRES * CS) return;
    out1[x] = bo[x % CS] + single[x];
}

// ---------------------------------------------------------------------------
// Frames v3: one thread per (n, h). Writes gq (n-major), gv (n-major), sqq,
// and j-major transposed kT[h][c][j], gkT[h][x][j], sqkT[h][j] for logits.
// ---------------------------------------------------------------------------
__global__ void frames_kernel(const float* __restrict__ proj, const float* __restrict__ rot,
                              const float* __restrict__ trans,
                              float* __restrict__ gq, float* __restrict__ gv,
                              float* __restrict__ sqq,
                              float* __restrict__ kT, float* __restrict__ gkT,
                              float* __restrict__ sqkT)
{
    int x = blockIdx.x * blockDim.x + threadIdx.x;
    if (x >= NRES * NH) return;
    int n = x / NH, h = x % NH;
    float R[9], t3[3];
#pragma unroll
    for (int r = 0; r < 9; ++r) R[r] = rot[n * 9 + r];
#pragma unroll
    for (int r = 0; r < 3; ++r) t3[r] = trans[n * 3 + r];
    const float* qp = proj + (size_t)n * PRJ + 576 + h * (PQ * 3);
    const float* kp = proj + (size_t)n * PRJ + 720 + h * (PQ * 3);
    const float* vp = proj + (size_t)n * PRJ + 864 + h * (PV * 3);
    const float* kk = proj + (size_t)n * PRJ + 192 + h * 16;

    // k transposed copy
#pragma unroll
    for (int c = 0; c < 16; ++c) kT[(h * 16 + c) * NRES + n] = kk[c];

    float sq = 0.f, sk = 0.f;
#pragma unroll
    for (int p = 0; p < PQ; ++p) {
        const float* in = qp + p * 3;
        float* og = gq + (size_t)n * 144 + h * (PQ * 3) + p * 3;
#pragma unroll
        for (int a = 0; a < 3; ++a) {
            float g = R[a*3+0]*in[0] + R[a*3+1]*in[1] + R[a*3+2]*in[2] + t3[a];
            og[a] = g; sq += g * g;
        }
        const float* in2 = kp + p * 3;
#pragma unroll
        for (int a = 0; a < 3; ++a) {
            float g = R[a*3+0]*in2[0] + R[a*3+1]*in2[1] + R[a*3+2]*in2[2] + t3[a];
            gkT[(h * 12 + p * 3 + a) * NRES + n] = g;
            sk += g * g;
        }
    }
    sqq[n * NH + h] = sq;
    sqkT[h * NRES + n] = sk;
#pragma unroll
    for (int p = 0; p < PV; ++p) {
        const float* in = vp + p * 3;
        float* og = gv + (size_t)n * 288 + h * (PV * 3) + p * 3;
#pragma unroll
        for (int a = 0; a < 3; ++a)
            og[a] = R[a*3+0]*in[0] + R[a*3+1]*in[1] + R[a*3+2]*in[2] + t3[a];
    }
}

// ---------------------------------------------------------------------------
// Logits v4: grid (i=512, jt=8), block 256 (4 waves). Bias via bf16 MFMA;
// qk/cross/d2 in f32 with fully coalesced j-major loads (kT/gkT/sqkT).
// ---------------------------------------------------------------------------
__global__ void logits_mfma_kernel(const float* __restrict__ pair, const float* __restrict__ proj,
                                   const float* __restrict__ gq, const float* __restrict__ kT,
                                   const float* __restrict__ gkT, const float* __restrict__ sqq,
                                   const float* __restrict__ sqkT, const float* __restrict__ Wb,
                                   const float* __restrict__ gamma_raw, float* __restrict__ L)
{
    __shared__ unsigned short pl[64 * 128];   // bf16, XOR-swizzled rows (16 KB)
    __shared__ float bias_s[64 * 17];
    __shared__ float qi[192], gqi[144], sqi[12], gam[12];

    int i = blockIdx.x, jt = blockIdx.y, t = threadIdx.x;
    int lane = t & 63, w = t >> 6;

    short8 bfrag[4];
    {
        int col = lane & 15;
        int kb = (lane >> 4) * 8;
#pragma unroll
        for (int ks = 0; ks < 4; ++ks) {
            short8 f;
#pragma unroll
            for (int e = 0; e < 8; ++e) {
                float v = (col < NH) ? Wb[(ks * 32 + kb + e) * NH + col] : 0.f;
                f[e] = (short)f2bf(v);
            }
            bfrag[ks] = f;
        }
    }

    for (int x = t; x < 192; x += 256) qi[x] = proj[(size_t)i * PRJ + x];
    for (int x = t; x < 144; x += 256) gqi[x] = gq[(size_t)i * 144 + x];
    if (t < 12) { sqi[t] = sqq[i * 12 + t]; gam[t] = softplusf(gamma_raw[t]); }

    const float* prow = pair + ((size_t)i * NRES + jt * 64) * CZ;
#pragma unroll
    for (int m = 0; m < 8; ++m) {
        int idx = m * 1024 + t * 4;
        int row = idx >> 7, kk = idx & 127;
        float4 v = *(const float4*)&prow[idx];
        unsigned b01 = (unsigned)f2bf(v.x) | ((unsigned)f2bf(v.y) << 16);
        unsigned b23 = (unsigned)f2bf(v.z) | ((unsigned)f2bf(v.w) << 16);
        int byte = row * 256 + ((kk * 2) ^ ((row & 7) << 4));
        *(uint2*)((char*)pl + byte) = make_uint2(b01, b23);
    }
    __syncthreads();

    {
        f32x4 acc = {0.f, 0.f, 0.f, 0.f};
        int arow = w * 16 + (lane & 15);
        int kb2 = (lane >> 4) * 16;
#pragma unroll
        for (int ks = 0; ks < 4; ++ks) {
            int byte = arow * 256 + (((ks * 64) + kb2) ^ ((arow & 7) << 4));
            short8 afrag = *(const short8*)((const char*)pl + byte);
            acc = __builtin_amdgcn_mfma_f32_16x16x32_bf16(afrag, bfrag[ks], acc, 0, 0, 0);
        }
        int crow = w * 16 + (lane >> 4) * 4;
        int ccol = lane & 15;
#pragma unroll
        for (int r = 0; r < 4; ++r) bias_s[(crow + r) * 17 + ccol] = acc[r];
    }
    __syncthreads();

    const float WLc = 0.57735026918962576f;
    const float WCc = 0.23570226039551584f;
    int j = jt * 64 + lane;
#pragma unroll
    for (int hh = 0; hh < 3; ++hh) {
        int h = w * 3 + hh;
        float qk = 0.f;
#pragma unroll
        for (int c = 0; c < 16; ++c)
            qk = fmaf(qi[h * 16 + c], kT[(h * 16 + c) * NRES + j], qk);
        float cross = 0.f;
#pragma unroll
        for (int x = 0; x < 12; ++x)
            cross = fmaf(gqi[h * 12 + x], gkT[(h * 12 + x) * NRES + j], cross);
        float d2 = sqi[h] + sqkT[h * NRES + j] - 2.f * cross;
        float logit = WLc * (qk * 0.25f + bias_s[lane * 17 + h] - 0.5f * WCc * gam[h] * d2);
        L[((size_t)i * NH + h) * NRES + j] = logit;
    }
}

// ---------------------------------------------------------------------------
// Softmax over j per (i,h) row, in place. grid = 6144, block = 256
// ---------------------------------------------------------------------------
__global__ void softmax_kernel(float* __restrict__ L)
{
    int row = blockIdx.x;
    float* p = L + (size_t)row * NRES;
    int t = threadIdx.x;
    __shared__ float red[256];
    float v0 = p[t], v1 = p[t + 256];
    red[t] = fmaxf(v0, v1);
    __syncthreads();
    for (int s = 128; s > 0; s >>= 1) { if (t < s) red[t] = fmaxf(red[t], red[t + s]); __syncthreads(); }
    float m = red[0];
    __syncthreads();
    float e0 = expf(v0 - m), e1 = expf(v1 - m);
    red[t] = e0 + e1;
    __syncthreads();
    for (int s = 128; s > 0; s >>= 1) { if (t < s) red[t] += red[t + s]; __syncthreads(); }
    float inv = 1.f / red[0];
    p[t] = e0 * inv;
    p[t + 256] = e1 * inv;
}

// ---------------------------------------------------------------------------
// o_pair: block per i, 384 threads = (32 z-quads x 12 heads)
// ---------------------------------------------------------------------------
__global__ void opair_kernel(const float* __restrict__ pair, const float* __restrict__ A,
                             float* __restrict__ concat)
{
    __shared__ float al[NH * NRES];
    int i = blockIdx.x, t = threadIdx.x;
    for (int x = t; x < NH * NRES / 4; x += 384)
        *(float4*)&al[x * 4] = *(const float4*)&A[(size_t)i * NH * NRES + x * 4];
    __syncthreads();
    int zq = t & 31, h = t >> 5;
    float4 acc = {0.f, 0.f, 0.f, 0.f};
    const float* pr = pair + (size_t)i * NRES * CZ;
    const float* ah = al + h * NRES;
    for (int j = 0; j < NRES; ++j) {
        float4 p4 = *(const float4*)&pr[(size_t)j * CZ + zq * 4];
        float a = ah[j];
        acc.x = fmaf(a, p4.x, acc.x);
        acc.y = fmaf(a, p4.y, acc.y);
        acc.z = fmaf(a, p4.z, acc.z);
        acc.w = fmaf(a, p4.w, acc.w);
    }
    *(float4*)&concat[(size_t)i * OUT_DIM + 576 + h * 128 + zq * 4] = acc;
}

// ---------------------------------------------------------------------------
// o_v, o_pt, local, norms -> concat[i, 0..575]
// ---------------------------------------------------------------------------
__global__ void ov_opt_kernel(const float* __restrict__ A, const float* __restrict__ proj,
                              const float* __restrict__ gv, const float* __restrict__ rot,
                              const float* __restrict__ trans, float* __restrict__ concat)
{
    int i = blockIdx.x, t = threadIdx.x;
    __shared__ float al[NH * NRES];
    __shared__ float opt[NH * PV * 3];
    for (int x = t; x < NH * NRES; x += 256) al[x] = A[(size_t)i * NH * NRES + x];
    __syncthreads();

    if (t < 192) {
        int h = t >> 4;
        float acc = 0.f;
        for (int j = 0; j < NRES; ++j)
            acc = fmaf(al[h * NRES + j], proj[(size_t)j * PRJ + 384 + t], acc);
        concat[(size_t)i * OUT_DIM + t] = acc;
    }
    for (int e = t; e < NH * PV * 3; e += 256) {
        int h = e / 24;
        float acc = 0.f;
        for (int j = 0; j < NRES; ++j) acc = fmaf(al[h * NRES + j], gv[(size_t)j * 288 + e], acc);
        opt[e] = acc;
    }
    __syncthreads();
    if (t < NH * PV) {
        int h = t >> 3, p = t & 7;
        float b0 = opt[h * 24 + p * 3 + 0] - trans[i * 3 + 0];
        float b1 = opt[h * 24 + p * 3 + 1] - trans[i * 3 + 1];
        float b2 = opt[h * 24 + p * 3 + 2] - trans[i * 3 + 2];
        const float* Ri = rot + i * 9;
        float l0 = Ri[0] * b0 + Ri[3] * b1 + Ri[6] * b2;
        float l1 = Ri[1] * b0 + Ri[4] * b1 + Ri[7] * b2;
        float l2 = Ri[2] * b0 + Ri[5] * b1 + Ri[8] * b2;
        float* c = concat + (size_t)i * OUT_DIM;
        c[192 + h * 24 + p * 3 + 0] = l0;
        c[192 + h * 24 + p * 3 + 1] = l1;
        c[192 + h * 24 + p * 3 + 2] = l2;
        c[480 + h * 8 + p] = sqrtf(l0 * l0 + l1 * l1 + l2 * l2 + 1e-8f);
    }
}

// ---------------------------------------------------------------------------
// LayerNorm over 384
// ---------------------------------------------------------------------------
__global__ void ln_kernel(const float* __restrict__ x, const float* __restrict__ g,
                          const float* __restrict__ b, float* __restrict__ y)
{
    int i = blockIdx.x, t = threadIdx.x;
    const float* xr = x + (size_t)i * CS;
    float a0 = xr[t], a1 = xr[t + 128], a2 = xr[t + 256];
    __shared__ float red[128];
    red[t] = a0 + a1 + a2;
    __syncthreads();
    for (int s = 64; s > 0; s >>= 1) { if (t < s) red[t] += red[t + s]; __syncthreads(); }
    float mean = red[0] * (1.f / CS);
    __syncthreads();
    float d0 = a0 - mean, d1 = a1 - mean, d2 = a2 - mean;
    red[t] = d0 * d0 + d1 * d1 + d2 * d2;
    __syncthreads();
    for (int s = 64; s > 0; s >>= 1) { if (t < s) red[t] += red[t + s]; __syncthreads(); }
    float rstd = rsqrtf(red[0] * (1.f / CS) + 1e-5f);
    float* yr = y + (size_t)i * CS;
    yr[t]       = d0 * rstd * g[t]       + b[t];
    yr[t + 128] = d1 * rstd * g[t + 128] + b[t + 128];
    yr[t + 256] = d2 * rstd * g[t + 256] + b[t + 256];
}

// ---------------------------------------------------------------------------
// Backbone: one block (128 thr) per residue; LDS reduce over 6 comps.
// ---------------------------------------------------------------------------
__global__ void backbone_kernel(const float* __restrict__ sfin, const float* __restrict__ Wbu,
                                const float* __restrict__ bbu, const float* __restrict__ rot,
                                const float* __restrict__ trans, float* __restrict__ rot_out,
                                float* __restrict__ trans_out)
{
    int i = blockIdx.x, t = threadIdx.x;
    float part[6] = {0.f, 0.f, 0.f, 0.f, 0.f, 0.f};
    for (int k = t; k < CS; k += 128) {
        float s = sfin[(size_t)i * CS + k];
        const float* wr = Wbu + k * 6;
#pragma unroll
        for (int c = 0; c < 6; ++c) part[c] = fmaf(s, wr[c], part[c]);
    }
    __shared__ float red[6][128];
#pragma unroll
    for (int c = 0; c < 6; ++c) red[c][t] = part[c];
    __syncthreads();
    for (int s = 64; s > 0; s >>= 1) {
        if (t < s) {
#pragma unroll
            for (int c = 0; c < 6; ++c) red[c][t] += red[c][t + s];
        }
        __syncthreads();
    }
    if (t == 0) {
        float u[6];
#pragma unroll
        for (int c = 0; c < 6; ++c) u[c] = red[c][0] + bbu[c];
        float a = 1.f, b = u[0], c2 = u[1], d = u[2];
        float inv = rsqrtf(a * a + b * b + c2 * c2 + d * d);
        a *= inv; b *= inv; c2 *= inv; d *= inv;
        float R[9] = { a*a + b*b - c2*c2 - d*d, 2.f*(b*c2 - a*d),        2.f*(b*d + a*c2),
                       2.f*(b*c2 + a*d),        a*a - b*b + c2*c2 - d*d, 2.f*(c2*d - a*b),
                       2.f*(b*d - a*c2),        2.f*(c2*d + a*b),        a*a - b*b - c2*c2 + d*d };
        const float* Ri = rot + i * 9;
        float Rn[9];
#pragma unroll
        for (int r = 0; r < 3; ++r)
#pragma unroll
            for (int cc = 0; cc < 3; ++cc) {
                float s2 = 0.f;
#pragma unroll
                for (int kk = 0; kk < 3; ++kk) s2 += Ri[r * 3 + kk] * R[kk * 3 + cc];
                Rn[r * 3 + cc] = s2;
            }
#pragma unroll
        for (int r = 0; r < 9; ++r) rot_out[i * 9 + r] = Rn[r];
        float t0 = u[3], t1 = u[4], t2 = u[5];
#pragma unroll
        for (int r = 0; r < 3; ++r)
            trans_out[i * 3 + r] = Ri[r * 3 + 0] * t0 + Ri[r * 3 + 1] * t1 + Ri[r * 3 + 2] * t2 + trans[i * 3 + r];
    }
}

// ---------------------------------------------------------------------------
// Loss
// ---------------------------------------------------------------------------
__global__ void loss_kernel(const float* __restrict__ rot_new, const float* __restrict__ trans_new,
                            const float* __restrict__ rot_truth, const float* __restrict__ trans_truth,
                            float* __restrict__ loss)
{
    int i = blockIdx.x;
    int t = threadIdx.x;
    __shared__ float red[256];
    float Rn[9], Rt[9];
#pragma unroll
    for (int r = 0; r < 9; ++r) { Rn[r] = rot_new[i * 9 + r]; Rt[r] = rot_truth[i * 9 + r]; }
    float ti0 = trans_new[i * 3 + 0], ti1 = trans_new[i * 3 + 1], ti2 = trans_new[i * 3 + 2];
    float tt0 = trans_truth[i * 3 + 0], tt1 = trans_truth[i * 3 + 1], tt2 = trans_truth[i * 3 + 2];
    float s = 0.f;
    for (int j = t; j < NRES; j += 256) {
        float db0 = trans_new[j * 3 + 0] - ti0;
        float db1 = trans_new[j * 3 + 1] - ti1;
        float db2 = trans_new[j * 3 + 2] - ti2;
        float dp0 = Rn[0] * db0 + Rn[3] * db1 + Rn[6] * db2;
        float dp1 = Rn[1] * db0 + Rn[4] * db1 + Rn[7] * db2;
        float dp2 = Rn[2] * db0 + Rn[5] * db1 + Rn[8] * db2;
        float eb0 = trans_truth[j * 3 + 0] - tt0;
        float eb1 = trans_truth[j * 3 + 1] - tt1;
        float eb2 = trans_truth[j * 3 + 2] - tt2;
        float dt0 = Rt[0] * eb0 + Rt[3] * eb1 + Rt[6] * eb2;
        float dt1 = Rt[1] * eb0 + Rt[4] * eb1 + Rt[7] * eb2;
        float dt2 = Rt[2] * eb0 + Rt[5] * eb1 + Rt[8] * eb2;
        float dx = dp0 - dt0, dy = dp1 - dt1, dz = dp2 - dt2;
        float dd = sqrtf(dx * dx + dy * dy + dz * dz + 1e-12f);
        s += fminf(dd, 10.f);
    }
    red[t] = s;
    __syncthreads();
    for (int k = 128; k > 0; k >>= 1) { if (t < k) red[t] += red[t + k]; __syncthreads(); }
    if (t == 0) atomicAdd(loss, red[0] * (1.f / (512.f * 512.f * 10.f)));
}

// ---------------------------------------------------------------------------
extern "C" void kernel_launch(void* const* d_in, const int* in_sizes, int n_in,
                              void* d_out, int out_size, void* d_ws, size_t ws_size,
                              hipStream_t stream)
{
    const float* single      = (const float*)d_in[0];
    const float* pair        = (const float*)d_in[1];
    const float* rot         = (const float*)d_in[2];
    const float* trans       = (const float*)d_in[3];
    const float* rot_truth   = (const float*)d_in[4];
    const float* trans_truth = (const float*)d_in[5];
    const float* Wq  = (const float*)d_in[6];
    const float* Wk  = (const float*)d_in[7];
    const float* Wv  = (const float*)d_in[8];
    const float* Wqp = (const float*)d_in[9];
    const float* Wkp = (const float*)d_in[10];
    const float* Wvp = (const float*)d_in[11];
    const float* Wb  = (const float*)d_in[12];
    const float* Wo  = (const float*)d_in[13];
    const float* bo  = (const float*)d_in[14];
    const float* gamma_raw = (const float*)d_in[15];
    const float* ln1_g = (const float*)d_in[16];
    const float* ln1_b = (const float*)d_in[17];
    const float* ln2_g = (const float*)d_in[18];
    const float* ln2_b = (const float*)d_in[19];
    const float* W1 = (const float*)d_in[20];
    const float* b1 = (const float*)d_in[21];
    const float* W2 = (const float*)d_in[22];
    const float* b2 = (const float*)d_in[23];
    const float* W3 = (const float*)d_in[24];
    const float* b3 = (const float*)d_in[25];
    const float* Wbu = (const float*)d_in[26];
    const float* bbu = (const float*)d_in[27];

    float* out = (float*)d_out;
    float* single_out = out;                   // 512*384
    float* rot_out    = out + 196608;          // 512*9
    float* trans_out  = out + 201216;          // 512*3
    float* loss_out   = out + 202752;          // 1

    float* ws = (float*)d_ws;
    float* proj   = ws;                         // 512*1152 = 589824
    float* gq     = proj   + 589824;            // 73728
    float* gv     = gq     + 73728;             // 147456
    float* sqq    = gv     + 147456;            // 6144
    float* kT     = sqq    + 6144;              // 98304
    float* gkT    = kT     + 98304;             // 73728
    float* sqkT   = gkT    + 73728;             // 6144
    float* Amat   = sqkT   + 6144;              // 512*12*512 = 3145728
    float* Bp     = Amat;                       // alias: used only before logits
    float* concat = Amat   + 3145728;           // 512*2112 = 1081344
    float* out1   = concat + 1081344;           // 196608
    float* sln    = out1   + 196608;            // 196608
    float* h1     = sln    + 196608;            // 196608
    float* h2     = h1     + 196608;            // 196608

    dim3 b256(256);

    // 1. pack projection weights, fused projection GEMM
    pack_proj_kernel<<<dim3((CS * PRJ + 255) / 256), b256, 0, stream>>>(Wq, Wk, Wv, Wqp, Wkp, Wvp, Bp);
    gemm_tiled<<<dim3(8, PRJ / 64, 1), b256, 0, stream>>>(single, Bp, nullptr, nullptr, proj,
                                                          NRES, CS, PRJ, 0, CS);

    // 2. frames (one thread per (n,h)), writes transposed k/gk/sqk
    frames_kernel<<<dim3((NRES * NH + 255) / 256), b256, 0, stream>>>(proj, rot, trans,
                                                                      gq, gv, sqq, kT, gkT, sqkT);

    // 3. logits (MFMA bias + coalesced f32) + softmax
    logits_mfma_kernel<<<dim3(NRES, 8), b256, 0, stream>>>(pair, proj, gq, kT, gkT, sqq, sqkT,
                                                           Wb, gamma_raw, Amat);
    softmax_kernel<<<dim3(NRES * NH), b256, 0, stream>>>(Amat);

    // 4. attention outputs
    opair_kernel<<<dim3(NRES), dim3(384), 0, stream>>>(pair, Amat, concat);
    ov_opt_kernel<<<dim3(NRES), b256, 0, stream>>>(Amat, proj, gv, rot, trans, concat);

    // 5. ipa_out = concat @ Wo + bo + single  (k-split=4, atomic into pre-init)
    init_out1_kernel<<<dim3((NRES * CS + 255) / 256), b256, 0, stream>>>(bo, single, out1);
    gemm_tiled<<<dim3(8, CS / 64, 4), b256, 0, stream>>>(concat, Wo, nullptr, nullptr, out1,
                                                         NRES, OUT_DIM, CS, 0, 528);

    // 6. LN1 + FF + LN2
    ln_kernel<<<dim3(NRES), dim3(128), 0, stream>>>(out1, ln1_g, ln1_b, sln);
    gemm_tiled<<<dim3(8, CS / 64, 1), b256, 0, stream>>>(sln, W1, b1, nullptr, h1, NRES, CS, CS, 1, CS);
    gemm_tiled<<<dim3(8, CS / 64, 1), b256, 0, stream>>>(h1, W2, b2, nullptr, h2, NRES, CS, CS, 1, CS);
    gemm_tiled<<<dim3(8, CS / 64, 1), b256, 0, stream>>>(h2, W3, b3, sln, out1, NRES, CS, CS, 0, CS);
    ln_kernel<<<dim3(NRES), dim3(128), 0, stream>>>(out1, ln2_g, ln2_b, single_out);

    // 7. backbone (block per residue) + loss
    backbone_kernel<<<dim3(NRES), dim3(128), 0, stream>>>(single_out, Wbu, bbu, rot, trans, rot_out, trans_out);
    hipMemsetAsync(loss_out, 0, sizeof(float), stream);
    loss_kernel<<<dim3(NRES), b256, 0, stream>>>(rot_out, trans_out, rot_truth, trans_truth, loss_out);
}